// Round 1
// baseline (1342.264 us; speedup 1.0000x reference)
//
#include <hip/hip_runtime.h>
#include <math.h>

// Problem constants
#define BB 4
#define LLL 1024
#define DDD 768
#define HHH 12
#define EEE 30
#define MMM 60
#define PPP 870
#define RRR 97
#define NNODE 120   // B*E
#define NPAIR 3480  // B*P
#define NEDGE 3600  // NPAIR + NNODE self loops
#define FMIN 1e-10f

// ---------------------------------------------------------------------------
// mention[b,m,d] = exp( sum_l mention_map[b,m,l] * context[b,l,d] )
__global__ __launch_bounds__(256) void k_mention(const float* __restrict__ ctx,
                                                 const float* __restrict__ mmap,
                                                 float* __restrict__ mention) {
  int bm = blockIdx.x;            // b*MMM + m
  int b = bm / MMM;
  const float* mrow = mmap + (size_t)bm * LLL;
  float acc[3] = {0.f, 0.f, 0.f};
  for (int l = 0; l < LLL; l++) {
    float w = mrow[l];
    if (w != 0.f) {
      const float* c = ctx + ((size_t)b * LLL + l) * DDD;
      #pragma unroll
      for (int q = 0; q < 3; q++) acc[q] += w * c[threadIdx.x + 256 * q];
    }
  }
  #pragma unroll
  for (int q = 0; q < 3; q++)
    mention[(size_t)bm * DDD + threadIdx.x + 256 * q] = expf(acc[q]);
}

// x[b,e,d] = log( sum_m entity_map[b,e,m] * mention[b,m,d] )  (0 if empty)
__global__ __launch_bounds__(256) void k_entity(const float* __restrict__ mention,
                                                const float* __restrict__ emap,
                                                float* __restrict__ x) {
  int be = blockIdx.x;            // b*EEE + e
  int b = be / EEE;
  float acc[3] = {0.f, 0.f, 0.f};
  float cnt = 0.f;
  for (int m = 0; m < MMM; m++) {
    float w = emap[(size_t)be * MMM + m];
    cnt += w;
    if (w != 0.f) {
      const float* mr = mention + ((size_t)b * MMM + m) * DDD;
      #pragma unroll
      for (int q = 0; q < 3; q++) acc[q] += w * mr[threadIdx.x + 256 * q];
    }
  }
  bool empty = (cnt == 0.f);
  #pragma unroll
  for (int q = 0; q < 3; q++)
    x[(size_t)be * DDD + threadIdx.x + 256 * q] = empty ? 0.f : logf(acc[q]);
}

// em[b,e,l] = sum_m entity_map[b,e,m]*mention_map[b,m,l]; normalized over l
__global__ __launch_bounds__(256) void k_em(const float* __restrict__ emap,
                                            const float* __restrict__ mmap,
                                            float* __restrict__ em) {
  int be = blockIdx.x;
  int b = be / EEE;
  int tid = threadIdx.x;
  float acc[4] = {0.f, 0.f, 0.f, 0.f};
  for (int m = 0; m < MMM; m++) {
    float w = emap[(size_t)be * MMM + m];
    if (w != 0.f) {
      const float* mr = mmap + ((size_t)b * MMM + m) * LLL;
      #pragma unroll
      for (int q = 0; q < 4; q++) acc[q] += w * mr[tid + 256 * q];
    }
  }
  __shared__ float red[256];
  red[tid] = acc[0] + acc[1] + acc[2] + acc[3];
  __syncthreads();
  for (int st = 128; st > 0; st >>= 1) {
    if (tid < st) red[tid] += red[tid + st];
    __syncthreads();
  }
  float inv = 1.f / (red[0] + FMIN);
  #pragma unroll
  for (int q = 0; q < 4; q++)
    em[(size_t)be * LLL + tid + 256 * q] = acc[q] * inv;
}

// compact nonzeros of em rows (deterministic order), one wave per row
__global__ __launch_bounds__(64) void k_emnz(const float* __restrict__ em,
                                             int* __restrict__ nzl,
                                             float* __restrict__ nzw,
                                             int* __restrict__ nzc) {
  int be = blockIdx.x;
  int lane = threadIdx.x;
  int base = 0;
  for (int l0 = 0; l0 < LLL; l0 += 64) {
    float w = em[(size_t)be * LLL + l0 + lane];
    unsigned long long mb = __ballot(w != 0.f);
    int pre = __popcll(mb & ((1ull << lane) - 1ull));
    if (w != 0.f) {
      nzl[be * LLL + base + pre] = l0 + lane;
      nzw[be * LLL + base + pre] = w;
    }
    base += __popcll(mb);
  }
  if (lane == 0) nzc[be] = base;
}

// ea[b,e,h,m] = sum_{nz l} w_l * attention[b,h,l,m]
__global__ __launch_bounds__(256) void k_ea(const float* __restrict__ attn,
                                            const int* __restrict__ nzl,
                                            const float* __restrict__ nzw,
                                            const int* __restrict__ nzc,
                                            float* __restrict__ ea) {
  int e = blockIdx.x, h = blockIdx.y, b = blockIdx.z;
  int be = b * EEE + e;
  int cnt = nzc[be];
  float acc[4] = {0.f, 0.f, 0.f, 0.f};
  for (int i = 0; i < cnt; i++) {
    int l = nzl[be * LLL + i];
    float w = nzw[be * LLL + i];
    const float* ar = attn + (((size_t)b * HHH + h) * LLL + l) * LLL;
    #pragma unroll
    for (int q = 0; q < 4; q++) acc[q] += w * ar[threadIdx.x + 256 * q];
  }
  float* er = ea + ((size_t)be * HHH + h) * LLL;
  #pragma unroll
  for (int q = 0; q < 4; q++) er[threadIdx.x + 256 * q] = acc[q];
}

// ca[b,p,l] = sum_h ea[b,hs,h,l]*ea[b,ts,h,l], row-normalized
__global__ __launch_bounds__(256) void k_ca(const float* __restrict__ ea,
                                            const int* __restrict__ hts,
                                            float* __restrict__ ca) {
  int bp = blockIdx.x;            // b*PPP + p
  int b = bp / PPP;
  int hs = hts[bp * 2 + 0], ts = hts[bp * 2 + 1];
  int tid = threadIdx.x;
  const float* eh = ea + ((size_t)(b * EEE + hs) * HHH) * LLL;
  const float* et = ea + ((size_t)(b * EEE + ts) * HHH) * LLL;
  float v[4];
  #pragma unroll
  for (int q = 0; q < 4; q++) {
    int l = tid + 256 * q;
    float s = 0.f;
    #pragma unroll
    for (int h = 0; h < HHH; h++)
      s += eh[(size_t)h * LLL + l] * et[(size_t)h * LLL + l];
    v[q] = s;
  }
  __shared__ float red[256];
  red[tid] = v[0] + v[1] + v[2] + v[3];
  __syncthreads();
  for (int st = 128; st > 0; st >>= 1) {
    if (tid < st) red[tid] += red[tid + st];
    __syncthreads();
  }
  float inv = 1.f / (red[0] + FMIN);
  #pragma unroll
  for (int q = 0; q < 4; q++)
    ca[(size_t)bp * LLL + tid + 256 * q] = v[q] * inv;
}

// ---------------------------------------------------------------------------
// generic tiled fp32 GEMM, 64x64 C tile, BK=16, 4x4 micro-tile, N is mult of 64
struct GArgs {
  const float *A, *B0, *B1, *B2;
  float *C0, *C1, *C2;
  const float *bias0, *bias1;
  const float *x, *cinfo, *nodes, *fout;
  const int *hts;
  int M, K;
};

// MODE 0: CINFO  (z=batch) A=ca[b], B=context[b], C=cinfo[b], mask epilogue
// MODE 1: FNX    (z=0/1/2) A=x, B=W_ni/W_nj/W_node, C=fni/fnj/fnode
// MODE 2: FFIJ   A gather: row<NPAIR?cinfo:x ; B=W_fij ; C=fout
// MODE 3: NEWHT  (z=0/1) A gather: c<768?nodes[b*E+hts[row,z]]:fout[row]; tanh(.+bias)
template <int MODE>
__global__ __launch_bounds__(256) void k_gemm(GArgs g) {
  __shared__ float As[16][68];
  __shared__ float Bs[16][68];
  int tid = threadIdx.x;
  int tx = tid & 15, ty = tid >> 4;
  int row0 = blockIdx.x * 64;
  int col0 = blockIdx.y * 64;
  int bz = blockIdx.z;

  const float* Bp;
  float* Cp;
  const float* bias = nullptr;
  if (MODE == 0) { Bp = g.B0 + (size_t)bz * LLL * DDD; Cp = g.C0 + (size_t)bz * PPP * DDD; }
  else if (MODE == 1) { Bp = bz == 0 ? g.B0 : (bz == 1 ? g.B1 : g.B2);
                        Cp = bz == 0 ? g.C0 : (bz == 1 ? g.C1 : g.C2); }
  else if (MODE == 2) { Bp = g.B0; Cp = g.C0; }
  else { Bp = bz ? g.B1 : g.B0; Cp = bz ? g.C1 : g.C0; bias = bz ? g.bias1 : g.bias0; }

  int am = tid >> 2, ak = (tid & 3) * 4;  // A loader: row am, 4 consecutive k
  int bk = tid >> 4, bn = (tid & 15) * 4; // B loader: row bk, 4 consecutive n

  float acc[4][4] = {};
  for (int k0 = 0; k0 < g.K; k0 += 16) {
    int row = row0 + am;
    float4 av = make_float4(0.f, 0.f, 0.f, 0.f);
    if (row < g.M) {
      int c = k0 + ak;
      const float* ap;
      if (MODE == 0) ap = g.A + ((size_t)bz * PPP + row) * LLL + c;
      else if (MODE == 1) ap = g.A + (size_t)row * DDD + c;
      else if (MODE == 2) ap = (row < NPAIR) ? g.cinfo + (size_t)row * DDD + c
                                             : g.x + (size_t)(row - NPAIR) * DDD + c;
      else {
        if (c < DDD) {
          int ht = g.hts[row * 2 + bz];
          int b = row / PPP;
          ap = g.nodes + (size_t)(b * EEE + ht) * DDD + c;
        } else {
          ap = g.fout + (size_t)row * DDD + (c - DDD);
        }
      }
      av = *(const float4*)ap;
    }
    As[ak + 0][am] = av.x; As[ak + 1][am] = av.y;
    As[ak + 2][am] = av.z; As[ak + 3][am] = av.w;
    float4 bv = *(const float4*)(Bp + (size_t)(k0 + bk) * DDD + col0 + bn);
    *(float4*)&Bs[bk][bn] = bv;
    __syncthreads();
    #pragma unroll
    for (int kk = 0; kk < 16; kk++) {
      float4 a4 = *(float4*)&As[kk][ty * 4];
      float4 b4 = *(float4*)&Bs[kk][tx * 4];
      acc[0][0] += a4.x * b4.x; acc[0][1] += a4.x * b4.y; acc[0][2] += a4.x * b4.z; acc[0][3] += a4.x * b4.w;
      acc[1][0] += a4.y * b4.x; acc[1][1] += a4.y * b4.y; acc[1][2] += a4.y * b4.z; acc[1][3] += a4.y * b4.w;
      acc[2][0] += a4.z * b4.x; acc[2][1] += a4.z * b4.y; acc[2][2] += a4.z * b4.z; acc[2][3] += a4.z * b4.w;
      acc[3][0] += a4.w * b4.x; acc[3][1] += a4.w * b4.y; acc[3][2] += a4.w * b4.z; acc[3][3] += a4.w * b4.w;
    }
    __syncthreads();
  }

  int col = col0 + tx * 4;
  #pragma unroll
  for (int i = 0; i < 4; i++) {
    int row = row0 + ty * 4 + i;
    if (row >= g.M) continue;
    float4 v = make_float4(acc[i][0], acc[i][1], acc[i][2], acc[i][3]);
    if (MODE == 0) {
      int h0 = g.hts[((size_t)bz * PPP + row) * 2 + 0];
      int h1 = g.hts[((size_t)bz * PPP + row) * 2 + 1];
      float mk = (h0 + h1 != 0) ? 1.f : 0.f;
      v.x *= mk; v.y *= mk; v.z *= mk; v.w *= mk;
    } else if (MODE == 3) {
      v.x = tanhf(v.x + bias[col + 0]); v.y = tanhf(v.y + bias[col + 1]);
      v.z = tanhf(v.z + bias[col + 2]); v.w = tanhf(v.w + bias[col + 3]);
    }
    *(float4*)&Cp[(size_t)row * DDD + col] = v;
  }
}

// ---------------------------------------------------------------------------
// f_out (in place on fout) += fni[src]+fnj[dst]+bias ; scores = sum_k lrelu*avec
__global__ __launch_bounds__(256) void k_scores(float* __restrict__ fout,
                                                const float* __restrict__ fni,
                                                const float* __restrict__ fnj,
                                                const float* __restrict__ bias,
                                                const float* __restrict__ avec,
                                                const int* __restrict__ hts,
                                                float* __restrict__ scores) {
  int e = blockIdx.x;
  int srcn, dstn;
  if (e < NPAIR) {
    int b = e / PPP;
    srcn = b * EEE + hts[e * 2 + 0];
    dstn = b * EEE + hts[e * 2 + 1];
  } else {
    srcn = dstn = e - NPAIR;
  }
  int lane = threadIdx.x & 63;
  #pragma unroll
  for (int q = 0; q < 3; q++) {
    int j = threadIdx.x + 256 * q;
    float v = fout[(size_t)e * DDD + j] + fni[(size_t)srcn * DDD + j] +
              fnj[(size_t)dstn * DDD + j] + bias[j];
    fout[(size_t)e * DDD + j] = v;
    float lr = v > 0.f ? v : 0.2f * v;
    float s = lr * avec[j];
    for (int off = 32; off > 0; off >>= 1) s += __shfl_xor(s, off, 64);
    if (lane == 0) scores[e * HHH + (j >> 6)] = s;
  }
}

// per-node edge softmax over in-edges + message aggregation
#define ECAP 256
__global__ __launch_bounds__(256) void k_agg(const float* __restrict__ scores,
                                             const float* __restrict__ fnode,
                                             const int* __restrict__ hts,
                                             float* __restrict__ nodes) {
  __shared__ int cnt;
  __shared__ int elist[ECAP], slist[ECAP];
  __shared__ float smax[HHH], ssum[HHH];
  __shared__ float alpha[ECAP * HHH];
  int n = blockIdx.x, tid = threadIdx.x;
  if (tid == 0) cnt = 0;
  __syncthreads();
  for (int e = tid; e < NEDGE; e += 256) {
    int srcn, dstn;
    if (e < NPAIR) {
      int b = e / PPP;
      srcn = b * EEE + hts[e * 2 + 0];
      dstn = b * EEE + hts[e * 2 + 1];
    } else {
      srcn = dstn = e - NPAIR;
    }
    if (dstn == n) {
      int i = atomicAdd(&cnt, 1);
      if (i < ECAP) { elist[i] = e; slist[i] = srcn; }
    }
  }
  __syncthreads();
  int c = min(cnt, ECAP);
  if (tid < HHH) {
    float m = -1e30f;
    for (int i = 0; i < c; i++) m = fmaxf(m, scores[elist[i] * HHH + tid]);
    smax[tid] = m;
    float s = 0.f;
    for (int i = 0; i < c; i++) s += expf(scores[elist[i] * HHH + tid] - m);
    ssum[tid] = s;
  }
  __syncthreads();
  for (int t = tid; t < c * HHH; t += 256) {
    int i = t / HHH, h = t - i * HHH;
    alpha[t] = expf(scores[elist[i] * HHH + h] - smax[h]) / ssum[h];
  }
  __syncthreads();
  for (int j = tid; j < DDD; j += 256) {
    int h = j >> 6;
    float acc = 0.f;
    for (int i = 0; i < c; i++)
      acc += alpha[i * HHH + h] * fnode[(size_t)slist[i] * DDD + j];
    nodes[(size_t)n * DDD + j] = acc;
  }
}

// ---------------------------------------------------------------------------
// out[pair,r] = b_rel[r]  (then bilinear atomically accumulates)
__global__ __launch_bounds__(256) void k_initout(const float* __restrict__ brel,
                                                 float* __restrict__ out) {
  int idx = blockIdx.x * 256 + threadIdx.x;
  if (idx < NPAIR * RRR) out[idx] = brel[idx % RRR];
}

// group bilinear: out[pair,r] += sum_{x,y} a[pair,k,x] b[pair,k,y] W[(k*64+x)*64+y, r]
// grid (pair_tiles=55, k=12); thread: tx=r lane (r=tx+16j, j<7), ty: 4 pairs
__global__ __launch_bounds__(256) void k_bilinear(const float* __restrict__ newh,
                                                  const float* __restrict__ newt,
                                                  const float* __restrict__ Wrel,
                                                  float* __restrict__ out) {
  __shared__ float bls[64][68];    // [y][p]
  __shared__ float wls[64][112];   // [y][r]
  __shared__ float acol[64];
  int tid = threadIdx.x;
  int k = blockIdx.y;
  int pt = blockIdx.x;
  int tx = tid & 15, ty = tid >> 4;

  for (int idx = tid; idx < 64 * 64; idx += 256) {
    int p = idx >> 6, y = idx & 63;
    int pair = pt * 64 + p;
    bls[y][p] = (pair < NPAIR) ? newt[(size_t)pair * DDD + k * 64 + y] : 0.f;
  }

  float acc[7][4] = {};
  for (int xx = 0; xx < 64; xx++) {
    __syncthreads();
    if (tid < 64) {
      int pair = pt * 64 + tid;
      acol[tid] = (pair < NPAIR) ? newh[(size_t)pair * DDD + k * 64 + xx] : 0.f;
    }
    {
      const float* wr = Wrel + (size_t)((k * 64 + xx) * 64) * RRR;
      for (int idx = tid; idx < 64 * RRR; idx += 256) {
        int y = idx / RRR, r = idx - y * RRR;
        wls[y][r] = wr[idx];
      }
    }
    __syncthreads();
    float a0 = acol[ty * 4 + 0], a1 = acol[ty * 4 + 1];
    float a2 = acol[ty * 4 + 2], a3 = acol[ty * 4 + 3];
    for (int y = 0; y < 64; y++) {
      float4 bv = *(float4*)&bls[y][ty * 4];
      float t0 = a0 * bv.x, t1 = a1 * bv.y, t2 = a2 * bv.z, t3 = a3 * bv.w;
      #pragma unroll
      for (int j = 0; j < 7; j++) {
        float w = wls[y][tx + 16 * j];
        acc[j][0] += t0 * w; acc[j][1] += t1 * w;
        acc[j][2] += t2 * w; acc[j][3] += t3 * w;
      }
    }
  }
  #pragma unroll
  for (int j = 0; j < 7; j++) {
    int r = tx + 16 * j;
    if (r < RRR) {
      #pragma unroll
      for (int i = 0; i < 4; i++) {
        int pair = pt * 64 + ty * 4 + i;
        if (pair < NPAIR) atomicAdd(&out[(size_t)pair * RRR + r], acc[j][i]);
      }
    }
  }
}

// ---------------------------------------------------------------------------
extern "C" void kernel_launch(void* const* d_in, const int* in_sizes, int n_in,
                              void* d_out, int out_size, void* d_ws, size_t ws_size,
                              hipStream_t stream) {
  const float* context   = (const float*)d_in[0];
  const float* attention = (const float*)d_in[1];
  const float* mmap      = (const float*)d_in[2];
  const float* emap      = (const float*)d_in[3];
  const int*   hts       = (const int*)d_in[4];
  const float* W_h       = (const float*)d_in[5];
  const float* b_h       = (const float*)d_in[6];
  const float* W_t       = (const float*)d_in[7];
  const float* b_t       = (const float*)d_in[8];
  const float* W_node    = (const float*)d_in[9];
  const float* W_ni      = (const float*)d_in[10];
  const float* W_nj      = (const float*)d_in[11];
  const float* W_fij     = (const float*)d_in[12];
  const float* egat_bias = (const float*)d_in[13];
  const float* attn_vec  = (const float*)d_in[14];
  const float* W_rel     = (const float*)d_in[15];
  const float* b_rel     = (const float*)d_in[16];
  float* out = (float*)d_out;

  float* ws = (float*)d_ws;
  size_t o = 0;
  auto alloc = [&](size_t n) { size_t r = o; o += (n + 63) & ~(size_t)63; return r; };
  size_t o_mention = alloc((size_t)BB * MMM * DDD);
  size_t o_x       = alloc((size_t)NNODE * DDD);
  size_t o_em      = alloc((size_t)BB * EEE * LLL);
  size_t o_ea      = alloc((size_t)BB * EEE * HHH * LLL);
  size_t o_ca      = alloc((size_t)NPAIR * LLL);       // reused as newh later
  size_t o_cinfo   = alloc((size_t)NPAIR * DDD);
  size_t o_fni     = alloc((size_t)NNODE * DDD);
  size_t o_fnj     = alloc((size_t)NNODE * DDD);
  size_t o_fnode   = alloc((size_t)NNODE * DDD);
  size_t o_fout    = alloc((size_t)NEDGE * DDD);
  size_t o_scores  = alloc((size_t)NEDGE * HHH);
  size_t o_nodes   = alloc((size_t)NNODE * DDD);
  size_t o_newt    = alloc((size_t)NPAIR * DDD);
  size_t o_nzl     = alloc((size_t)BB * EEE * LLL);
  size_t o_nzw     = alloc((size_t)BB * EEE * LLL);
  size_t o_nzc     = alloc(128);
  (void)ws_size; // ~57 MB used

  float* mention = ws + o_mention;
  float* x       = ws + o_x;
  float* em      = ws + o_em;
  float* ea      = ws + o_ea;
  float* ca      = ws + o_ca;
  float* cinfo   = ws + o_cinfo;
  float* fni     = ws + o_fni;
  float* fnj     = ws + o_fnj;
  float* fnode   = ws + o_fnode;
  float* fout    = ws + o_fout;
  float* scores  = ws + o_scores;
  float* nodes   = ws + o_nodes;
  float* newh    = ca;              // overlay: ca dead after CINFO gemm
  float* newt    = ws + o_newt;
  int*   nzl     = (int*)(ws + o_nzl);
  float* nzw     = ws + o_nzw;
  int*   nzc     = (int*)(ws + o_nzc);

  k_mention<<<BB * MMM, 256, 0, stream>>>(context, mmap, mention);
  k_entity<<<BB * EEE, 256, 0, stream>>>(mention, emap, x);
  k_em<<<BB * EEE, 256, 0, stream>>>(emap, mmap, em);
  k_emnz<<<BB * EEE, 64, 0, stream>>>(em, nzl, nzw, nzc);
  k_ea<<<dim3(EEE, HHH, BB), 256, 0, stream>>>(attention, nzl, nzw, nzc, ea);
  k_ca<<<BB * PPP, 256, 0, stream>>>(ea, hts, ca);

  GArgs gc = {};
  gc.A = ca; gc.B0 = context; gc.C0 = cinfo; gc.hts = hts; gc.M = PPP; gc.K = LLL;
  k_gemm<0><<<dim3(14, 12, BB), 256, 0, stream>>>(gc);

  GArgs gf = {};
  gf.A = x; gf.B0 = W_ni; gf.B1 = W_nj; gf.B2 = W_node;
  gf.C0 = fni; gf.C1 = fnj; gf.C2 = fnode; gf.M = NNODE; gf.K = DDD;
  k_gemm<1><<<dim3(2, 12, 3), 256, 0, stream>>>(gf);

  GArgs gj = {};
  gj.B0 = W_fij; gj.C0 = fout; gj.cinfo = cinfo; gj.x = x; gj.M = NEDGE; gj.K = DDD;
  k_gemm<2><<<dim3(57, 12, 1), 256, 0, stream>>>(gj);

  k_scores<<<NEDGE, 256, 0, stream>>>(fout, fni, fnj, egat_bias, attn_vec, hts, scores);
  k_agg<<<NNODE, 256, 0, stream>>>(scores, fnode, hts, nodes);

  GArgs gn = {};
  gn.B0 = W_h; gn.B1 = W_t; gn.bias0 = b_h; gn.bias1 = b_t;
  gn.C0 = newh; gn.C1 = newt; gn.nodes = nodes; gn.fout = fout; gn.hts = hts;
  gn.M = NPAIR; gn.K = 2 * DDD;
  k_gemm<3><<<dim3(55, 12, 2), 256, 0, stream>>>(gn);

  k_initout<<<(NPAIR * RRR + 255) / 256, 256, 0, stream>>>(b_rel, out);
  k_bilinear<<<dim3(55, 12), 256, 0, stream>>>(newh, newt, W_rel, out);
}

// Round 2
// 836.612 us; speedup vs baseline: 1.6044x; 1.6044x over previous
//
#include <hip/hip_runtime.h>
#include <math.h>

// Problem constants
#define BB 4
#define LLL 1024
#define DDD 768
#define HHH 12
#define EEE 30
#define MMM 60
#define PPP 870
#define RRR 97
#define NNODE 120   // B*E
#define NPAIR 3480  // B*P
#define NEDGE 3600  // NPAIR + NNODE self loops
#define FMIN 1e-10f

typedef __attribute__((ext_vector_type(8))) __bf16 bf16x8;
typedef __attribute__((ext_vector_type(8))) short short8;
typedef __attribute__((ext_vector_type(4))) float f32x4;

// ---------------------------------------------------------------------------
// mention[b,m,d] = exp( sum_l mention_map[b,m,l] * context[b,l,d] )
__global__ __launch_bounds__(256) void k_mention(const float* __restrict__ ctx,
                                                 const float* __restrict__ mmap,
                                                 float* __restrict__ mention) {
  int bm = blockIdx.x;            // b*MMM + m
  int b = bm / MMM;
  const float* mrow = mmap + (size_t)bm * LLL;
  float acc[3] = {0.f, 0.f, 0.f};
  for (int l = 0; l < LLL; l++) {
    float w = mrow[l];
    if (w != 0.f) {
      const float* c = ctx + ((size_t)b * LLL + l) * DDD;
      #pragma unroll
      for (int q = 0; q < 3; q++) acc[q] += w * c[threadIdx.x + 256 * q];
    }
  }
  #pragma unroll
  for (int q = 0; q < 3; q++)
    mention[(size_t)bm * DDD + threadIdx.x + 256 * q] = expf(acc[q]);
}

// x[b,e,d] = log( sum_m entity_map[b,e,m] * mention[b,m,d] )  (0 if empty)
__global__ __launch_bounds__(256) void k_entity(const float* __restrict__ mention,
                                                const float* __restrict__ emap,
                                                float* __restrict__ x) {
  int be = blockIdx.x;            // b*EEE + e
  int b = be / EEE;
  float acc[3] = {0.f, 0.f, 0.f};
  float cnt = 0.f;
  for (int m = 0; m < MMM; m++) {
    float w = emap[(size_t)be * MMM + m];
    cnt += w;
    if (w != 0.f) {
      const float* mr = mention + ((size_t)b * MMM + m) * DDD;
      #pragma unroll
      for (int q = 0; q < 3; q++) acc[q] += w * mr[threadIdx.x + 256 * q];
    }
  }
  bool empty = (cnt == 0.f);
  #pragma unroll
  for (int q = 0; q < 3; q++)
    x[(size_t)be * DDD + threadIdx.x + 256 * q] = empty ? 0.f : logf(acc[q]);
}

// em[b,e,l] = sum_m entity_map[b,e,m]*mention_map[b,m,l]; normalized over l
__global__ __launch_bounds__(256) void k_em(const float* __restrict__ emap,
                                            const float* __restrict__ mmap,
                                            float* __restrict__ em) {
  int be = blockIdx.x;
  int b = be / EEE;
  int tid = threadIdx.x;
  float acc[4] = {0.f, 0.f, 0.f, 0.f};
  for (int m = 0; m < MMM; m++) {
    float w = emap[(size_t)be * MMM + m];
    if (w != 0.f) {
      const float* mr = mmap + ((size_t)b * MMM + m) * LLL;
      #pragma unroll
      for (int q = 0; q < 4; q++) acc[q] += w * mr[tid + 256 * q];
    }
  }
  __shared__ float red[256];
  red[tid] = acc[0] + acc[1] + acc[2] + acc[3];
  __syncthreads();
  for (int st = 128; st > 0; st >>= 1) {
    if (tid < st) red[tid] += red[tid + st];
    __syncthreads();
  }
  float inv = 1.f / (red[0] + FMIN);
  #pragma unroll
  for (int q = 0; q < 4; q++)
    em[(size_t)be * LLL + tid + 256 * q] = acc[q] * inv;
}

// compact nonzeros of em rows (deterministic order), one wave per row
__global__ __launch_bounds__(64) void k_emnz(const float* __restrict__ em,
                                             int* __restrict__ nzl,
                                             float* __restrict__ nzw,
                                             int* __restrict__ nzc) {
  int be = blockIdx.x;
  int lane = threadIdx.x;
  int base = 0;
  for (int l0 = 0; l0 < LLL; l0 += 64) {
    float w = em[(size_t)be * LLL + l0 + lane];
    unsigned long long mb = __ballot(w != 0.f);
    int pre = __popcll(mb & ((1ull << lane) - 1ull));
    if (w != 0.f) {
      nzl[be * LLL + base + pre] = l0 + lane;
      nzw[be * LLL + base + pre] = w;
    }
    base += __popcll(mb);
  }
  if (lane == 0) nzc[be] = base;
}

// ea[b,e,h,m] = sum_{nz l} w_l * attention[b,h,l,m]
__global__ __launch_bounds__(256) void k_ea(const float* __restrict__ attn,
                                            const int* __restrict__ nzl,
                                            const float* __restrict__ nzw,
                                            const int* __restrict__ nzc,
                                            float* __restrict__ ea) {
  int e = blockIdx.x, h = blockIdx.y, b = blockIdx.z;
  int be = b * EEE + e;
  int cnt = nzc[be];
  float acc[4] = {0.f, 0.f, 0.f, 0.f};
  for (int i = 0; i < cnt; i++) {
    int l = nzl[be * LLL + i];
    float w = nzw[be * LLL + i];
    const float* ar = attn + (((size_t)b * HHH + h) * LLL + l) * LLL;
    #pragma unroll
    for (int q = 0; q < 4; q++) acc[q] += w * ar[threadIdx.x + 256 * q];
  }
  float* er = ea + ((size_t)be * HHH + h) * LLL;
  #pragma unroll
  for (int q = 0; q < 4; q++) er[threadIdx.x + 256 * q] = acc[q];
}

// ca[b,p,l] = sum_h ea[b,hs,h,l]*ea[b,ts,h,l], row-normalized
__global__ __launch_bounds__(256) void k_ca(const float* __restrict__ ea,
                                            const int* __restrict__ hts,
                                            float* __restrict__ ca) {
  int bp = blockIdx.x;            // b*PPP + p
  int b = bp / PPP;
  int hs = hts[bp * 2 + 0], ts = hts[bp * 2 + 1];
  int tid = threadIdx.x;
  const float* eh = ea + ((size_t)(b * EEE + hs) * HHH) * LLL;
  const float* et = ea + ((size_t)(b * EEE + ts) * HHH) * LLL;
  float v[4];
  #pragma unroll
  for (int q = 0; q < 4; q++) {
    int l = tid + 256 * q;
    float s = 0.f;
    #pragma unroll
    for (int h = 0; h < HHH; h++)
      s += eh[(size_t)h * LLL + l] * et[(size_t)h * LLL + l];
    v[q] = s;
  }
  __shared__ float red[256];
  red[tid] = v[0] + v[1] + v[2] + v[3];
  __syncthreads();
  for (int st = 128; st > 0; st >>= 1) {
    if (tid < st) red[tid] += red[tid + st];
    __syncthreads();
  }
  float inv = 1.f / (red[0] + FMIN);
  #pragma unroll
  for (int q = 0; q < 4; q++)
    ca[(size_t)bp * LLL + tid + 256 * q] = v[q] * inv;
}

// ---------------------------------------------------------------------------
// generic tiled fp32 GEMM, 64x64 C tile, BK=16, 4x4 micro-tile, N is mult of 64
struct GArgs {
  const float *A, *B0, *B1, *B2;
  float *C0, *C1, *C2;
  const float *bias0, *bias1;
  const float *x, *cinfo, *nodes, *fout;
  const int *hts;
  int M, K;
};

// MODE 0: CINFO  (z=batch) A=ca[b], B=context[b], C=cinfo[b], mask epilogue
// MODE 1: FNX    (z=0/1/2) A=x, B=W_ni/W_nj/W_node, C=fni/fnj/fnode
// MODE 2: FFIJ   A gather: row<NPAIR?cinfo:x ; B=W_fij ; C=fout
// MODE 3: NEWHT  (z=0/1) A gather: c<768?nodes[b*E+hts[row,z]]:fout[row]; tanh(.+bias)
template <int MODE>
__global__ __launch_bounds__(256) void k_gemm(GArgs g) {
  __shared__ float As[16][68];
  __shared__ float Bs[16][68];
  int tid = threadIdx.x;
  int tx = tid & 15, ty = tid >> 4;
  int row0 = blockIdx.x * 64;
  int col0 = blockIdx.y * 64;
  int bz = blockIdx.z;

  const float* Bp;
  float* Cp;
  const float* bias = nullptr;
  if (MODE == 0) { Bp = g.B0 + (size_t)bz * LLL * DDD; Cp = g.C0 + (size_t)bz * PPP * DDD; }
  else if (MODE == 1) { Bp = bz == 0 ? g.B0 : (bz == 1 ? g.B1 : g.B2);
                        Cp = bz == 0 ? g.C0 : (bz == 1 ? g.C1 : g.C2); }
  else if (MODE == 2) { Bp = g.B0; Cp = g.C0; }
  else { Bp = bz ? g.B1 : g.B0; Cp = bz ? g.C1 : g.C0; bias = bz ? g.bias1 : g.bias0; }

  int am = tid >> 2, ak = (tid & 3) * 4;  // A loader: row am, 4 consecutive k
  int bk = tid >> 4, bn = (tid & 15) * 4; // B loader: row bk, 4 consecutive n

  float acc[4][4] = {};
  for (int k0 = 0; k0 < g.K; k0 += 16) {
    int row = row0 + am;
    float4 av = make_float4(0.f, 0.f, 0.f, 0.f);
    if (row < g.M) {
      int c = k0 + ak;
      const float* ap;
      if (MODE == 0) ap = g.A + ((size_t)bz * PPP + row) * LLL + c;
      else if (MODE == 1) ap = g.A + (size_t)row * DDD + c;
      else if (MODE == 2) ap = (row < NPAIR) ? g.cinfo + (size_t)row * DDD + c
                                             : g.x + (size_t)(row - NPAIR) * DDD + c;
      else {
        if (c < DDD) {
          int ht = g.hts[row * 2 + bz];
          int b = row / PPP;
          ap = g.nodes + (size_t)(b * EEE + ht) * DDD + c;
        } else {
          ap = g.fout + (size_t)row * DDD + (c - DDD);
        }
      }
      av = *(const float4*)ap;
    }
    As[ak + 0][am] = av.x; As[ak + 1][am] = av.y;
    As[ak + 2][am] = av.z; As[ak + 3][am] = av.w;
    float4 bv = *(const float4*)(Bp + (size_t)(k0 + bk) * DDD + col0 + bn);
    *(float4*)&Bs[bk][bn] = bv;
    __syncthreads();
    #pragma unroll
    for (int kk = 0; kk < 16; kk++) {
      float4 a4 = *(float4*)&As[kk][ty * 4];
      float4 b4 = *(float4*)&Bs[kk][tx * 4];
      acc[0][0] += a4.x * b4.x; acc[0][1] += a4.x * b4.y; acc[0][2] += a4.x * b4.z; acc[0][3] += a4.x * b4.w;
      acc[1][0] += a4.y * b4.x; acc[1][1] += a4.y * b4.y; acc[1][2] += a4.y * b4.z; acc[1][3] += a4.y * b4.w;
      acc[2][0] += a4.z * b4.x; acc[2][1] += a4.z * b4.y; acc[2][2] += a4.z * b4.z; acc[2][3] += a4.z * b4.w;
      acc[3][0] += a4.w * b4.x; acc[3][1] += a4.w * b4.y; acc[3][2] += a4.w * b4.z; acc[3][3] += a4.w * b4.w;
    }
    __syncthreads();
  }

  int col = col0 + tx * 4;
  #pragma unroll
  for (int i = 0; i < 4; i++) {
    int row = row0 + ty * 4 + i;
    if (row >= g.M) continue;
    float4 v = make_float4(acc[i][0], acc[i][1], acc[i][2], acc[i][3]);
    if (MODE == 0) {
      int h0 = g.hts[((size_t)bz * PPP + row) * 2 + 0];
      int h1 = g.hts[((size_t)bz * PPP + row) * 2 + 1];
      float mk = (h0 + h1 != 0) ? 1.f : 0.f;
      v.x *= mk; v.y *= mk; v.z *= mk; v.w *= mk;
    } else if (MODE == 3) {
      v.x = tanhf(v.x + bias[col + 0]); v.y = tanhf(v.y + bias[col + 1]);
      v.z = tanhf(v.z + bias[col + 2]); v.w = tanhf(v.w + bias[col + 3]);
    }
    *(float4*)&Cp[(size_t)row * DDD + col] = v;
  }
}

// ---------------------------------------------------------------------------
// f_out (in place on fout) += fni[src]+fnj[dst]+bias ; scores = sum_k lrelu*avec
__global__ __launch_bounds__(256) void k_scores(float* __restrict__ fout,
                                                const float* __restrict__ fni,
                                                const float* __restrict__ fnj,
                                                const float* __restrict__ bias,
                                                const float* __restrict__ avec,
                                                const int* __restrict__ hts,
                                                float* __restrict__ scores) {
  int e = blockIdx.x;
  int srcn, dstn;
  if (e < NPAIR) {
    int b = e / PPP;
    srcn = b * EEE + hts[e * 2 + 0];
    dstn = b * EEE + hts[e * 2 + 1];
  } else {
    srcn = dstn = e - NPAIR;
  }
  int lane = threadIdx.x & 63;
  #pragma unroll
  for (int q = 0; q < 3; q++) {
    int j = threadIdx.x + 256 * q;
    float v = fout[(size_t)e * DDD + j] + fni[(size_t)srcn * DDD + j] +
              fnj[(size_t)dstn * DDD + j] + bias[j];
    fout[(size_t)e * DDD + j] = v;
    float lr = v > 0.f ? v : 0.2f * v;
    float s = lr * avec[j];
    for (int off = 32; off > 0; off >>= 1) s += __shfl_xor(s, off, 64);
    if (lane == 0) scores[e * HHH + (j >> 6)] = s;
  }
}

// per-node edge softmax over in-edges + message aggregation
#define ECAP 256
__global__ __launch_bounds__(256) void k_agg(const float* __restrict__ scores,
                                             const float* __restrict__ fnode,
                                             const int* __restrict__ hts,
                                             float* __restrict__ nodes) {
  __shared__ int cnt;
  __shared__ int elist[ECAP], slist[ECAP];
  __shared__ float smax[HHH], ssum[HHH];
  __shared__ float alpha[ECAP * HHH];
  int n = blockIdx.x, tid = threadIdx.x;
  if (tid == 0) cnt = 0;
  __syncthreads();
  for (int e = tid; e < NEDGE; e += 256) {
    int srcn, dstn;
    if (e < NPAIR) {
      int b = e / PPP;
      srcn = b * EEE + hts[e * 2 + 0];
      dstn = b * EEE + hts[e * 2 + 1];
    } else {
      srcn = dstn = e - NPAIR;
    }
    if (dstn == n) {
      int i = atomicAdd(&cnt, 1);
      if (i < ECAP) { elist[i] = e; slist[i] = srcn; }
    }
  }
  __syncthreads();
  int c = min(cnt, ECAP);
  if (tid < HHH) {
    float m = -1e30f;
    for (int i = 0; i < c; i++) m = fmaxf(m, scores[elist[i] * HHH + tid]);
    smax[tid] = m;
    float s = 0.f;
    for (int i = 0; i < c; i++) s += expf(scores[elist[i] * HHH + tid] - m);
    ssum[tid] = s;
  }
  __syncthreads();
  for (int t = tid; t < c * HHH; t += 256) {
    int i = t / HHH, h = t - i * HHH;
    alpha[t] = expf(scores[elist[i] * HHH + h] - smax[h]) / ssum[h];
  }
  __syncthreads();
  for (int j = tid; j < DDD; j += 256) {
    int h = j >> 6;
    float acc = 0.f;
    for (int i = 0; i < c; i++)
      acc += alpha[i * HHH + h] * fnode[(size_t)slist[i] * DDD + j];
    nodes[(size_t)n * DDD + j] = acc;
  }
}

// ---------------------------------------------------------------------------
// out[pair,r] = b_rel[r]  (then bilinear atomically accumulates)
__global__ __launch_bounds__(256) void k_initout(const float* __restrict__ brel,
                                                 float* __restrict__ out) {
  int idx = blockIdx.x * 256 + threadIdx.x;
  if (idx < NPAIR * RRR) out[idx] = brel[idx % RRR];
}

// ---------------------------------------------------------------------------
// Prepass: transpose+convert W_rel into bf16 chunks for MFMA B-operand.
// Chunk c = kg*64 + x covers W_rel rows [c*64, c*64+64), i.e. (k=kg, x, y=0..63).
// Stored layout per chunk (7168 bf16 = 14336 B): r-major [112][64], with the
// 16B y-slot XOR-swizzled: physical slot jj holds logical slot j = jj ^ (r&7).
// Rows r in [97,112) are zero padding.
__global__ __launch_bounds__(256) void k_wprep(const float* __restrict__ Wrel,
                                               unsigned short* __restrict__ tW) {
  __shared__ float w_s[64][98];
  int c = blockIdx.x;
  int tid = threadIdx.x;
  for (int idx = tid; idx < 64 * 97; idx += 256) {
    int y = idx / 97, r = idx - y * 97;
    w_s[y][r] = Wrel[(size_t)(c * 64 + y) * RRR + r];
  }
  __syncthreads();
  for (int odx = tid; odx < 7168; odx += 256) {
    int r = odx >> 6, pos = odx & 63;
    int jj = pos >> 3, e = pos & 7;
    int y = ((jj ^ (r & 7)) << 3) + e;
    float v = (r < RRR) ? w_s[y][r] : 0.f;
    tW[(size_t)c * 7168 + odx] = __builtin_bit_cast(unsigned short, (__bf16)v);
  }
}

// ---------------------------------------------------------------------------
// Group-bilinear as bf16 MFMA GEMM: out[p,r] += sum_{x,y} a[p,k,x] b[p,k,y] W[kxy,r]
// Block: 64 pairs (4 M-tiles) x one k-group; 4 waves split the 7 N-tiles (N=112).
// A-fragment G[m][y] = bf16(a[m][x]*b[m][y]) generated in-register; W streamed
// through double-buffered LDS (issue-early / write-late), swizzled reads.
__global__ __launch_bounds__(256) void k_bilinear_mfma(
    const float* __restrict__ newh, const float* __restrict__ newt,
    const unsigned short* __restrict__ tW, float* __restrict__ out) {
  __shared__ float a_s[64][64];             // [x][p] transposed
  __shared__ unsigned short wbuf[2][7168];  // double-buffered W chunk
  int tid = threadIdx.x;
  int lane = tid & 63;
  int wv = tid >> 6;
  int l15 = lane & 15, l4 = lane >> 4;
  int pt = blockIdx.x, kg = blockIdx.y;

  // ---- stage a transposed: a_s[x][p] = newh[pt*64+p][kg*64+x] ----
  {
    int pl = tid >> 2, xq = (tid & 3) * 16;
    int prow = pt * 64 + pl; if (prow >= NPAIR) prow = NPAIR - 1;
    const float* src = newh + (size_t)prow * DDD + kg * 64 + xq;
    #pragma unroll
    for (int j4 = 0; j4 < 4; j4++) {
      float4 v = *(const float4*)(src + j4 * 4);
      a_s[xq + j4 * 4 + 0][pl] = v.x;
      a_s[xq + j4 * 4 + 1][pl] = v.y;
      a_s[xq + j4 * 4 + 2][pl] = v.z;
      a_s[xq + j4 * 4 + 3][pl] = v.w;
    }
  }

  // ---- hoist b into registers: breg[t][h][i] = b[m=t*16+l15][y=h*32+8*l4+i] ----
  float breg[4][2][8];
  #pragma unroll
  for (int t = 0; t < 4; t++) {
    int prow = pt * 64 + t * 16 + l15; if (prow >= NPAIR) prow = NPAIR - 1;
    const float* src = newt + (size_t)prow * DDD + kg * 64 + 8 * l4;
    #pragma unroll
    for (int h = 0; h < 2; h++) {
      float4 v0 = *(const float4*)(src + h * 32);
      float4 v1 = *(const float4*)(src + h * 32 + 4);
      breg[t][h][0] = v0.x; breg[t][h][1] = v0.y; breg[t][h][2] = v0.z; breg[t][h][3] = v0.w;
      breg[t][h][4] = v1.x; breg[t][h][5] = v1.y; breg[t][h][6] = v1.z; breg[t][h][7] = v1.w;
    }
  }

  // ---- prologue: stage chunk x=0 into wbuf[0] ----
  {
    const unsigned short* src0 = tW + (size_t)(kg * 64) * 7168;
    #pragma unroll
    for (int i = 0; i < 3; i++)
      *(uint4*)&wbuf[0][(tid + 256 * i) * 8] = *(const uint4*)(src0 + (size_t)(tid + 256 * i) * 8);
    if (tid < 128)
      *(uint4*)&wbuf[0][(tid + 768) * 8] = *(const uint4*)(src0 + (size_t)(tid + 768) * 8);
  }
  __syncthreads();

  f32x4 zero = {0.f, 0.f, 0.f, 0.f};
  f32x4 acc[4][2];
  #pragma unroll
  for (int t = 0; t < 4; t++) { acc[t][0] = zero; acc[t][1] = zero; }

  for (int x = 0; x < 64; x++) {
    int cur = x & 1;
    // issue next chunk's global loads early (write to LDS after compute)
    uint4 st[4];
    if (x < 63) {
      const unsigned short* nsrc = tW + (size_t)(kg * 64 + x + 1) * 7168;
      #pragma unroll
      for (int i = 0; i < 3; i++) st[i] = *(const uint4*)(nsrc + (size_t)(tid + 256 * i) * 8);
      if (tid < 128) st[3] = *(const uint4*)(nsrc + (size_t)(tid + 768) * 8);
    }

    float av[4];
    #pragma unroll
    for (int t = 0; t < 4; t++) av[t] = a_s[x][t * 16 + l15];

    #pragma unroll
    for (int h = 0; h < 2; h++) {
      short8 g[4];
      #pragma unroll
      for (int t = 0; t < 4; t++) {
        bf16x8 gv;
        #pragma unroll
        for (int i = 0; i < 8; i++) gv[i] = (__bf16)(av[t] * breg[t][h][i]);
        g[t] = __builtin_bit_cast(short8, gv);
      }
      #pragma unroll
      for (int n = 0; n < 2; n++) {
        int nt = wv * 2 + n;
        if (nt < 7) {                       // wave-uniform
          int r = nt * 16 + l15;
          int phys = (h * 4 + l4) ^ (r & 7);
          short8 wf = __builtin_bit_cast(short8, *(const uint4*)&wbuf[cur][r * 64 + phys * 8]);
          #pragma unroll
          for (int t = 0; t < 4; t++)
            acc[t][n] = __builtin_amdgcn_mfma_f32_16x16x32_bf16(g[t], wf, acc[t][n], 0, 0, 0);
        }
      }
    }

    if (x < 63) {
      #pragma unroll
      for (int i = 0; i < 3; i++) *(uint4*)&wbuf[cur ^ 1][(tid + 256 * i) * 8] = st[i];
      if (tid < 128) *(uint4*)&wbuf[cur ^ 1][(tid + 768) * 8] = st[3];
    }
    __syncthreads();
  }

  // ---- epilogue: p = pt*64 + t*16 + l4*4 + q, r = nt*16 + l15 ----
  #pragma unroll
  for (int n = 0; n < 2; n++) {
    int nt = wv * 2 + n;
    if (nt >= 7) continue;
    int r = nt * 16 + l15;
    if (r >= RRR) continue;
    #pragma unroll
    for (int t = 0; t < 4; t++) {
      int pbase = pt * 64 + t * 16 + l4 * 4;
      #pragma unroll
      for (int q = 0; q < 4; q++) {
        int p = pbase + q;
        if (p < NPAIR) atomicAdd(&out[(size_t)p * RRR + r], acc[t][n][q]);
      }
    }
  }
}

// ---------------------------------------------------------------------------
extern "C" void kernel_launch(void* const* d_in, const int* in_sizes, int n_in,
                              void* d_out, int out_size, void* d_ws, size_t ws_size,
                              hipStream_t stream) {
  const float* context   = (const float*)d_in[0];
  const float* attention = (const float*)d_in[1];
  const float* mmap      = (const float*)d_in[2];
  const float* emap      = (const float*)d_in[3];
  const int*   hts       = (const int*)d_in[4];
  const float* W_h       = (const float*)d_in[5];
  const float* b_h       = (const float*)d_in[6];
  const float* W_t       = (const float*)d_in[7];
  const float* b_t       = (const float*)d_in[8];
  const float* W_node    = (const float*)d_in[9];
  const float* W_ni      = (const float*)d_in[10];
  const float* W_nj      = (const float*)d_in[11];
  const float* W_fij     = (const float*)d_in[12];
  const float* egat_bias = (const float*)d_in[13];
  const float* attn_vec  = (const float*)d_in[14];
  const float* W_rel     = (const float*)d_in[15];
  const float* b_rel     = (const float*)d_in[16];
  float* out = (float*)d_out;

  float* ws = (float*)d_ws;
  size_t o = 0;
  auto alloc = [&](size_t n) { size_t r = o; o += (n + 63) & ~(size_t)63; return r; };
  size_t o_mention = alloc((size_t)BB * MMM * DDD);
  size_t o_x       = alloc((size_t)NNODE * DDD);
  size_t o_em      = alloc((size_t)BB * EEE * LLL);
  size_t o_ea      = alloc((size_t)BB * EEE * HHH * LLL);
  size_t o_ca      = alloc((size_t)NPAIR * LLL);       // reused as newh later
  size_t o_cinfo   = alloc((size_t)NPAIR * DDD);
  size_t o_fni     = alloc((size_t)NNODE * DDD);
  size_t o_fnj     = alloc((size_t)NNODE * DDD);
  size_t o_fnode   = alloc((size_t)NNODE * DDD);
  size_t o_fout    = alloc((size_t)NEDGE * DDD);
  size_t o_scores  = alloc((size_t)NEDGE * HHH);
  size_t o_nodes   = alloc((size_t)NNODE * DDD);
  size_t o_newt    = alloc((size_t)NPAIR * DDD);
  size_t o_nzl     = alloc((size_t)BB * EEE * LLL);
  size_t o_nzw     = alloc((size_t)BB * EEE * LLL);
  size_t o_nzc     = alloc(128);
  size_t o_tw      = alloc((size_t)768 * 7168 / 2 + 64);  // bf16 chunks (11 MB)
  (void)ws_size; // ~68 MB used

  float* mention = ws + o_mention;
  float* x       = ws + o_x;
  float* em      = ws + o_em;
  float* ea      = ws + o_ea;
  float* ca      = ws + o_ca;
  float* cinfo   = ws + o_cinfo;
  float* fni     = ws + o_fni;
  float* fnj     = ws + o_fnj;
  float* fnode   = ws + o_fnode;
  float* fout    = ws + o_fout;
  float* scores  = ws + o_scores;
  float* nodes   = ws + o_nodes;
  float* newh    = ca;              // overlay: ca dead after CINFO gemm
  float* newt    = ws + o_newt;
  int*   nzl     = (int*)(ws + o_nzl);
  float* nzw     = ws + o_nzw;
  int*   nzc     = (int*)(ws + o_nzc);
  unsigned short* tW = (unsigned short*)(ws + o_tw);

  k_wprep<<<768, 256, 0, stream>>>(W_rel, tW);

  k_mention<<<BB * MMM, 256, 0, stream>>>(context, mmap, mention);
  k_entity<<<BB * EEE, 256, 0, stream>>>(mention, emap, x);
  k_em<<<BB * EEE, 256, 0, stream>>>(emap, mmap, em);
  k_emnz<<<BB * EEE, 64, 0, stream>>>(em, nzl, nzw, nzc);
  k_ea<<<dim3(EEE, HHH, BB), 256, 0, stream>>>(attention, nzl, nzw, nzc, ea);
  k_ca<<<BB * PPP, 256, 0, stream>>>(ea, hts, ca);

  GArgs gc = {};
  gc.A = ca; gc.B0 = context; gc.C0 = cinfo; gc.hts = hts; gc.M = PPP; gc.K = LLL;
  k_gemm<0><<<dim3(14, 12, BB), 256, 0, stream>>>(gc);

  GArgs gf = {};
  gf.A = x; gf.B0 = W_ni; gf.B1 = W_nj; gf.B2 = W_node;
  gf.C0 = fni; gf.C1 = fnj; gf.C2 = fnode; gf.M = NNODE; gf.K = DDD;
  k_gemm<1><<<dim3(2, 12, 3), 256, 0, stream>>>(gf);

  GArgs gj = {};
  gj.B0 = W_fij; gj.C0 = fout; gj.cinfo = cinfo; gj.x = x; gj.M = NEDGE; gj.K = DDD;
  k_gemm<2><<<dim3(57, 12, 1), 256, 0, stream>>>(gj);

  k_scores<<<NEDGE, 256, 0, stream>>>(fout, fni, fnj, egat_bias, attn_vec, hts, scores);
  k_agg<<<NNODE, 256, 0, stream>>>(scores, fnode, hts, nodes);

  GArgs gn = {};
  gn.B0 = W_h; gn.B1 = W_t; gn.bias0 = b_h; gn.bias1 = b_t;
  gn.C0 = newh; gn.C1 = newt; gn.nodes = nodes; gn.fout = fout; gn.hts = hts;
  gn.M = NPAIR; gn.K = 2 * DDD;
  k_gemm<3><<<dim3(55, 12, 2), 256, 0, stream>>>(gn);

  k_initout<<<(NPAIR * RRR + 255) / 256, 256, 0, stream>>>(b_rel, out);
  k_bilinear_mfma<<<dim3(55, 12), 256, 0, stream>>>(newh, newt, tW, out);
}

// Round 3
// 570.315 us; speedup vs baseline: 2.3535x; 1.4669x over previous
//
#include <hip/hip_runtime.h>
#include <math.h>

// Problem constants
#define BB 4
#define LLL 1024
#define DDD 768
#define HHH 12
#define EEE 30
#define MMM 60
#define PPP 870
#define RRR 97
#define NNODE 120   // B*E
#define NPAIR 3480  // B*P
#define NEDGE 3600  // NPAIR + NNODE self loops
#define FMIN 1e-10f

typedef __attribute__((ext_vector_type(8))) __bf16 bf16x8;
typedef __attribute__((ext_vector_type(8))) short short8;
typedef __attribute__((ext_vector_type(4))) float f32x4;

static __device__ __forceinline__ unsigned short f2bf(float v) {
  return __builtin_bit_cast(unsigned short, (__bf16)v);
}

// ---------------------------------------------------------------------------
// mention[b,m,d] = exp( sum_l mention_map[b,m,l] * context[b,l,d] )
__global__ __launch_bounds__(256) void k_mention(const float* __restrict__ ctx,
                                                 const float* __restrict__ mmap,
                                                 float* __restrict__ mention) {
  int bm = blockIdx.x;            // b*MMM + m
  int b = bm / MMM;
  const float* mrow = mmap + (size_t)bm * LLL;
  float acc[3] = {0.f, 0.f, 0.f};
  for (int l = 0; l < LLL; l++) {
    float w = mrow[l];
    if (w != 0.f) {
      const float* c = ctx + ((size_t)b * LLL + l) * DDD;
      #pragma unroll
      for (int q = 0; q < 3; q++) acc[q] += w * c[threadIdx.x + 256 * q];
    }
  }
  #pragma unroll
  for (int q = 0; q < 3; q++)
    mention[(size_t)bm * DDD + threadIdx.x + 256 * q] = expf(acc[q]);
}

// x[b,e,d] = log( sum_m entity_map[b,e,m] * mention[b,m,d] )  (0 if empty) -> bf16
__global__ __launch_bounds__(256) void k_entity(const float* __restrict__ mention,
                                                const float* __restrict__ emap,
                                                unsigned short* __restrict__ xb) {
  int be = blockIdx.x;            // b*EEE + e
  int b = be / EEE;
  float acc[3] = {0.f, 0.f, 0.f};
  float cnt = 0.f;
  for (int m = 0; m < MMM; m++) {
    float w = emap[(size_t)be * MMM + m];
    cnt += w;
    if (w != 0.f) {
      const float* mr = mention + ((size_t)b * MMM + m) * DDD;
      #pragma unroll
      for (int q = 0; q < 3; q++) acc[q] += w * mr[threadIdx.x + 256 * q];
    }
  }
  bool empty = (cnt == 0.f);
  #pragma unroll
  for (int q = 0; q < 3; q++)
    xb[(size_t)be * DDD + threadIdx.x + 256 * q] = f2bf(empty ? 0.f : logf(acc[q]));
}

// em[b,e,l] = sum_m entity_map[b,e,m]*mention_map[b,m,l]; normalized over l
__global__ __launch_bounds__(256) void k_em(const float* __restrict__ emap,
                                            const float* __restrict__ mmap,
                                            float* __restrict__ em) {
  int be = blockIdx.x;
  int b = be / EEE;
  int tid = threadIdx.x;
  float acc[4] = {0.f, 0.f, 0.f, 0.f};
  for (int m = 0; m < MMM; m++) {
    float w = emap[(size_t)be * MMM + m];
    if (w != 0.f) {
      const float* mr = mmap + ((size_t)b * MMM + m) * LLL;
      #pragma unroll
      for (int q = 0; q < 4; q++) acc[q] += w * mr[tid + 256 * q];
    }
  }
  __shared__ float red[256];
  red[tid] = acc[0] + acc[1] + acc[2] + acc[3];
  __syncthreads();
  for (int st = 128; st > 0; st >>= 1) {
    if (tid < st) red[tid] += red[tid + st];
    __syncthreads();
  }
  float inv = 1.f / (red[0] + FMIN);
  #pragma unroll
  for (int q = 0; q < 4; q++)
    em[(size_t)be * LLL + tid + 256 * q] = acc[q] * inv;
}

// compact nonzeros of em rows (deterministic order), one wave per row
__global__ __launch_bounds__(64) void k_emnz(const float* __restrict__ em,
                                             int* __restrict__ nzl,
                                             float* __restrict__ nzw,
                                             int* __restrict__ nzc) {
  int be = blockIdx.x;
  int lane = threadIdx.x;
  int base = 0;
  for (int l0 = 0; l0 < LLL; l0 += 64) {
    float w = em[(size_t)be * LLL + l0 + lane];
    unsigned long long mb = __ballot(w != 0.f);
    int pre = __popcll(mb & ((1ull << lane) - 1ull));
    if (w != 0.f) {
      nzl[be * LLL + base + pre] = l0 + lane;
      nzw[be * LLL + base + pre] = w;
    }
    base += __popcll(mb);
  }
  if (lane == 0) nzc[be] = base;
}

// ea[b,e,h,m] = sum_{nz l} w_l * attention[b,h,l,m]
__global__ __launch_bounds__(256) void k_ea(const float* __restrict__ attn,
                                            const int* __restrict__ nzl,
                                            const float* __restrict__ nzw,
                                            const int* __restrict__ nzc,
                                            float* __restrict__ ea) {
  int e = blockIdx.x, h = blockIdx.y, b = blockIdx.z;
  int be = b * EEE + e;
  int cnt = nzc[be];
  float acc[4] = {0.f, 0.f, 0.f, 0.f};
  for (int i = 0; i < cnt; i++) {
    int l = nzl[be * LLL + i];
    float w = nzw[be * LLL + i];
    const float* ar = attn + (((size_t)b * HHH + h) * LLL + l) * LLL;
    #pragma unroll
    for (int q = 0; q < 4; q++) acc[q] += w * ar[threadIdx.x + 256 * q];
  }
  float* er = ea + ((size_t)be * HHH + h) * LLL;
  #pragma unroll
  for (int q = 0; q < 4; q++) er[threadIdx.x + 256 * q] = acc[q];
}

// ca[b,p,l] = sum_h ea[b,hs,h,l]*ea[b,ts,h,l], row-normalized -> bf16
__global__ __launch_bounds__(256) void k_ca(const float* __restrict__ ea,
                                            const int* __restrict__ hts,
                                            unsigned short* __restrict__ cab) {
  int bp = blockIdx.x;            // b*PPP + p
  int b = bp / PPP;
  int hs = hts[bp * 2 + 0], ts = hts[bp * 2 + 1];
  int tid = threadIdx.x;
  const float* eh = ea + ((size_t)(b * EEE + hs) * HHH) * LLL;
  const float* et = ea + ((size_t)(b * EEE + ts) * HHH) * LLL;
  float v[4];
  #pragma unroll
  for (int q = 0; q < 4; q++) {
    int l = tid + 256 * q;
    float s = 0.f;
    #pragma unroll
    for (int h = 0; h < HHH; h++)
      s += eh[(size_t)h * LLL + l] * et[(size_t)h * LLL + l];
    v[q] = s;
  }
  __shared__ float red[256];
  red[tid] = v[0] + v[1] + v[2] + v[3];
  __syncthreads();
  for (int st = 128; st > 0; st >>= 1) {
    if (tid < st) red[tid] += red[tid + st];
    __syncthreads();
  }
  float inv = 1.f / (red[0] + FMIN);
  #pragma unroll
  for (int q = 0; q < 4; q++)
    cab[(size_t)bp * LLL + tid + 256 * q] = f2bf(v[q] * inv);
}

// ---------------------------------------------------------------------------
// transpose + fp32->bf16: src [z][R][C] fp32  ->  dst [z][C][R] bf16
__global__ __launch_bounds__(256) void k_transpose(const float* __restrict__ src,
                                                   unsigned short* __restrict__ dst,
                                                   int R, int C) {
  __shared__ float t_s[32][33];
  int c0 = blockIdx.x * 32, r0 = blockIdx.y * 32;
  const float* s = src + (size_t)blockIdx.z * R * C;
  unsigned short* d = dst + (size_t)blockIdx.z * R * C;
  int tx = threadIdx.x & 31, ty = threadIdx.x >> 5;
  #pragma unroll
  for (int i = 0; i < 4; i++)
    t_s[ty + i * 8][tx] = s[(size_t)(r0 + ty + i * 8) * C + c0 + tx];
  __syncthreads();
  #pragma unroll
  for (int i = 0; i < 4; i++)
    d[(size_t)(c0 + ty + i * 8) * R + r0 + tx] = f2bf(t_s[tx][ty + i * 8]);
}

// ---------------------------------------------------------------------------
// bf16 MFMA GEMM, 128x128 tile, BK=32, 4 waves (2x2), double-buffered LDS.
// A: [M][K] bf16 row-major (gathered per MODE); B: BT [N][K] bf16 row-major.
// LDS tiles stored [128 rows][32 k] with 16B granules XOR-swizzled by (row>>1)&3.
struct MGArgs {
  const unsigned short *A, *A2, *BT0, *BT1, *BT2, *nodes;
  float *C0, *C1, *C2;
  unsigned short *Cb;
  const float *bias0, *bias1;
  const int *hts;
  int M, K;
};

// MODE 0 CINFO: z=batch. A=cab rows (K=1024), BT=ctxT[z], C=cinfo bf16, ht-mask
// MODE 1 FNX:   z=0/1/2. A=xb (K=768), BT=wt_{ni,nj,node}, C=fni/fnj/fnode fp32
// MODE 2 FFIJ:  A gather row<NPAIR?cinfo:xb, BT=wtfij, C=fout fp32
// MODE 3 NEWHT: z=0/1. A gather k<768?nodesb[hts]:foutb, BT=wt_{h,t}, C=tanh(+bias)
template <int MODE>
__global__ __launch_bounds__(256) void k_mgemm(MGArgs g) {
  __shared__ unsigned short As[2][128 * 32];
  __shared__ unsigned short Bs[2][128 * 32];
  int tid = threadIdx.x;
  int lane = tid & 63;
  int wv = tid >> 6;
  int l15 = lane & 15, l4 = lane >> 4;
  int wr = wv >> 1, wc = wv & 1;
  int row0 = blockIdx.x * 128, col0 = blockIdx.y * 128;
  int bz = blockIdx.z;
  int K = g.K;

  const unsigned short* BTp;
  if (MODE == 0) BTp = g.BT0 + (size_t)bz * DDD * LLL;
  else if (MODE == 1) BTp = bz == 0 ? g.BT0 : (bz == 1 ? g.BT1 : g.BT2);
  else if (MODE == 2) BTp = g.BT0;
  else BTp = bz ? g.BT1 : g.BT0;

  // A granule pointer (element granularity), row pre-clamped
  auto aptr = [&](int grow, int k) -> const unsigned short* {
    if (MODE == 0) return g.A + ((size_t)(bz * PPP) + grow) * LLL + k;
    else if (MODE == 1) return g.A + (size_t)grow * DDD + k;
    else if (MODE == 2) return (grow < NPAIR) ? g.A + (size_t)grow * DDD + k
                                              : g.A2 + (size_t)(grow - NPAIR) * DDD + k;
    else {
      if (k < DDD) {
        int b = grow / PPP;
        int node = b * EEE + g.hts[grow * 2 + bz];
        return g.nodes + (size_t)node * DDD + k;
      }
      return g.A2 + (size_t)grow * DDD + (k - DDD);
    }
  };

  uint4 ar[2], br[2];
  auto load_tile = [&](int t) {
    #pragma unroll
    for (int i = 0; i < 2; i++) {
      int idx = i * 256 + tid;
      int row = idx >> 2, gg = idx & 3;
      int grow = row0 + row; if (grow >= g.M) grow = g.M - 1;
      ar[i] = *(const uint4*)aptr(grow, t * 32 + gg * 8);
      br[i] = *(const uint4*)(BTp + (size_t)(col0 + row) * K + t * 32 + gg * 8);
    }
  };
  auto write_tile = [&](int buf) {
    #pragma unroll
    for (int i = 0; i < 2; i++) {
      int idx = i * 256 + tid;
      int row = idx >> 2, gg = idx & 3;
      int phys = gg ^ ((row >> 1) & 3);
      *(uint4*)&As[buf][row * 32 + phys * 8] = ar[i];
      *(uint4*)&Bs[buf][row * 32 + phys * 8] = br[i];
    }
  };

  f32x4 zero = {0.f, 0.f, 0.f, 0.f};
  f32x4 acc[4][4];
  #pragma unroll
  for (int m = 0; m < 4; m++)
    #pragma unroll
    for (int n = 0; n < 4; n++) acc[m][n] = zero;

  int nt = K / 32;
  load_tile(0);
  write_tile(0);
  __syncthreads();
  int cur = 0;
  for (int t = 0; t < nt; t++) {
    if (t + 1 < nt) load_tile(t + 1);
    short8 af[4], bfr[4];
    #pragma unroll
    for (int m = 0; m < 4; m++) {
      int row = wr * 64 + m * 16 + l15;
      int phys = l4 ^ ((row >> 1) & 3);
      af[m] = *(const short8*)&As[cur][row * 32 + phys * 8];
    }
    #pragma unroll
    for (int n = 0; n < 4; n++) {
      int row = wc * 64 + n * 16 + l15;
      int phys = l4 ^ ((row >> 1) & 3);
      bfr[n] = *(const short8*)&Bs[cur][row * 32 + phys * 8];
    }
    #pragma unroll
    for (int m = 0; m < 4; m++)
      #pragma unroll
      for (int n = 0; n < 4; n++)
        acc[m][n] = __builtin_amdgcn_mfma_f32_16x16x32_bf16(af[m], bfr[n], acc[m][n], 0, 0, 0);
    if (t + 1 < nt) {
      write_tile(cur ^ 1);
      __syncthreads();
    }
    cur ^= 1;
  }

  // epilogue: row = row0 + wr*64 + m*16 + l4*4 + q ; col = col0 + wc*64 + n*16 + l15
  #pragma unroll
  for (int m = 0; m < 4; m++) {
    int rbase = row0 + wr * 64 + m * 16 + l4 * 4;
    #pragma unroll
    for (int n = 0; n < 4; n++) {
      int col = col0 + wc * 64 + n * 16 + l15;
      #pragma unroll
      for (int q = 0; q < 4; q++) {
        int r = rbase + q;
        if (r >= g.M) continue;
        float v = acc[m][n][q];
        if (MODE == 0) {
          size_t grow = (size_t)bz * PPP + r;
          int h0 = g.hts[grow * 2 + 0], h1 = g.hts[grow * 2 + 1];
          float mk = (h0 + h1 != 0) ? 1.f : 0.f;
          g.Cb[grow * DDD + col] = f2bf(v * mk);
        } else if (MODE == 1) {
          float* C = bz == 0 ? g.C0 : (bz == 1 ? g.C1 : g.C2);
          C[(size_t)r * DDD + col] = v;
        } else if (MODE == 2) {
          g.C0[(size_t)r * DDD + col] = v;
        } else {
          float* C = bz ? g.C1 : g.C0;
          const float* bias = bz ? g.bias1 : g.bias0;
          C[(size_t)r * DDD + col] = tanhf(v + bias[col]);
        }
      }
    }
  }
}

// ---------------------------------------------------------------------------
// f_out (in place, fp32) += fni[src]+fnj[dst]+bias ; bf16 copy; per-head scores
__global__ __launch_bounds__(256) void k_scores(float* __restrict__ fout,
                                                unsigned short* __restrict__ foutb,
                                                const float* __restrict__ fni,
                                                const float* __restrict__ fnj,
                                                const float* __restrict__ bias,
                                                const float* __restrict__ avec,
                                                const int* __restrict__ hts,
                                                float* __restrict__ scores) {
  int e = blockIdx.x;
  int srcn, dstn;
  if (e < NPAIR) {
    int b = e / PPP;
    srcn = b * EEE + hts[e * 2 + 0];
    dstn = b * EEE + hts[e * 2 + 1];
  } else {
    srcn = dstn = e - NPAIR;
  }
  int lane = threadIdx.x & 63;
  #pragma unroll
  for (int q = 0; q < 3; q++) {
    int j = threadIdx.x + 256 * q;
    float v = fout[(size_t)e * DDD + j] + fni[(size_t)srcn * DDD + j] +
              fnj[(size_t)dstn * DDD + j] + bias[j];
    fout[(size_t)e * DDD + j] = v;
    foutb[(size_t)e * DDD + j] = f2bf(v);
    float lr = v > 0.f ? v : 0.2f * v;
    float s = lr * avec[j];
    for (int off = 32; off > 0; off >>= 1) s += __shfl_xor(s, off, 64);
    if (lane == 0) scores[e * HHH + (j >> 6)] = s;
  }
}

// per-node edge softmax over in-edges + message aggregation -> nodes bf16
#define ECAP 256
__global__ __launch_bounds__(256) void k_agg(const float* __restrict__ scores,
                                             const float* __restrict__ fnode,
                                             const int* __restrict__ hts,
                                             unsigned short* __restrict__ nodesb) {
  __shared__ int cnt;
  __shared__ int elist[ECAP], slist[ECAP];
  __shared__ float smax[HHH], ssum[HHH];
  __shared__ float alpha[ECAP * HHH];
  int n = blockIdx.x, tid = threadIdx.x;
  if (tid == 0) cnt = 0;
  __syncthreads();
  for (int e = tid; e < NEDGE; e += 256) {
    int srcn, dstn;
    if (e < NPAIR) {
      int b = e / PPP;
      srcn = b * EEE + hts[e * 2 + 0];
      dstn = b * EEE + hts[e * 2 + 1];
    } else {
      srcn = dstn = e - NPAIR;
    }
    if (dstn == n) {
      int i = atomicAdd(&cnt, 1);
      if (i < ECAP) { elist[i] = e; slist[i] = srcn; }
    }
  }
  __syncthreads();
  int c = min(cnt, ECAP);
  if (tid < HHH) {
    float m = -1e30f;
    for (int i = 0; i < c; i++) m = fmaxf(m, scores[elist[i] * HHH + tid]);
    smax[tid] = m;
    float s = 0.f;
    for (int i = 0; i < c; i++) s += expf(scores[elist[i] * HHH + tid] - m);
    ssum[tid] = s;
  }
  __syncthreads();
  for (int t = tid; t < c * HHH; t += 256) {
    int i = t / HHH, h = t - i * HHH;
    alpha[t] = expf(scores[elist[i] * HHH + h] - smax[h]) / ssum[h];
  }
  __syncthreads();
  for (int j = tid; j < DDD; j += 256) {
    int h = j >> 6;
    float acc = 0.f;
    for (int i = 0; i < c; i++)
      acc += alpha[i * HHH + h] * fnode[(size_t)slist[i] * DDD + j];
    nodesb[(size_t)n * DDD + j] = f2bf(acc);
  }
}

// ---------------------------------------------------------------------------
// out[pair,r] = b_rel[r]  (then bilinear atomically accumulates)
__global__ __launch_bounds__(256) void k_initout(const float* __restrict__ brel,
                                                 float* __restrict__ out) {
  int idx = blockIdx.x * 256 + threadIdx.x;
  if (idx < NPAIR * RRR) out[idx] = brel[idx % RRR];
}

// ---------------------------------------------------------------------------
// Prepass: transpose+convert W_rel into bf16 chunks for bilinear MFMA B-operand.
__global__ __launch_bounds__(256) void k_wprep(const float* __restrict__ Wrel,
                                               unsigned short* __restrict__ tW) {
  __shared__ float w_s[64][98];
  int c = blockIdx.x;
  int tid = threadIdx.x;
  for (int idx = tid; idx < 64 * 97; idx += 256) {
    int y = idx / 97, r = idx - y * 97;
    w_s[y][r] = Wrel[(size_t)(c * 64 + y) * RRR + r];
  }
  __syncthreads();
  for (int odx = tid; odx < 7168; odx += 256) {
    int r = odx >> 6, pos = odx & 63;
    int jj = pos >> 3, e = pos & 7;
    int y = ((jj ^ (r & 7)) << 3) + e;
    float v = (r < RRR) ? w_s[y][r] : 0.f;
    tW[(size_t)c * 7168 + odx] = f2bf(v);
  }
}

// ---------------------------------------------------------------------------
// Group-bilinear as bf16 MFMA GEMM (see round 2)
__global__ __launch_bounds__(256) void k_bilinear_mfma(
    const float* __restrict__ newh, const float* __restrict__ newt,
    const unsigned short* __restrict__ tW, float* __restrict__ out) {
  __shared__ float a_s[64][64];             // [x][p] transposed
  __shared__ unsigned short wbuf[2][7168];  // double-buffered W chunk
  int tid = threadIdx.x;
  int lane = tid & 63;
  int wv = tid >> 6;
  int l15 = lane & 15, l4 = lane >> 4;
  int pt = blockIdx.x, kg = blockIdx.y;

  {
    int pl = tid >> 2, xq = (tid & 3) * 16;
    int prow = pt * 64 + pl; if (prow >= NPAIR) prow = NPAIR - 1;
    const float* src = newh + (size_t)prow * DDD + kg * 64 + xq;
    #pragma unroll
    for (int j4 = 0; j4 < 4; j4++) {
      float4 v = *(const float4*)(src + j4 * 4);
      a_s[xq + j4 * 4 + 0][pl] = v.x;
      a_s[xq + j4 * 4 + 1][pl] = v.y;
      a_s[xq + j4 * 4 + 2][pl] = v.z;
      a_s[xq + j4 * 4 + 3][pl] = v.w;
    }
  }

  float breg[4][2][8];
  #pragma unroll
  for (int t = 0; t < 4; t++) {
    int prow = pt * 64 + t * 16 + l15; if (prow >= NPAIR) prow = NPAIR - 1;
    const float* src = newt + (size_t)prow * DDD + kg * 64 + 8 * l4;
    #pragma unroll
    for (int h = 0; h < 2; h++) {
      float4 v0 = *(const float4*)(src + h * 32);
      float4 v1 = *(const float4*)(src + h * 32 + 4);
      breg[t][h][0] = v0.x; breg[t][h][1] = v0.y; breg[t][h][2] = v0.z; breg[t][h][3] = v0.w;
      breg[t][h][4] = v1.x; breg[t][h][5] = v1.y; breg[t][h][6] = v1.z; breg[t][h][7] = v1.w;
    }
  }

  {
    const unsigned short* src0 = tW + (size_t)(kg * 64) * 7168;
    #pragma unroll
    for (int i = 0; i < 3; i++)
      *(uint4*)&wbuf[0][(tid + 256 * i) * 8] = *(const uint4*)(src0 + (size_t)(tid + 256 * i) * 8);
    if (tid < 128)
      *(uint4*)&wbuf[0][(tid + 768) * 8] = *(const uint4*)(src0 + (size_t)(tid + 768) * 8);
  }
  __syncthreads();

  f32x4 zero = {0.f, 0.f, 0.f, 0.f};
  f32x4 acc[4][2];
  #pragma unroll
  for (int t = 0; t < 4; t++) { acc[t][0] = zero; acc[t][1] = zero; }

  for (int x = 0; x < 64; x++) {
    int cur = x & 1;
    uint4 st[4];
    if (x < 63) {
      const unsigned short* nsrc = tW + (size_t)(kg * 64 + x + 1) * 7168;
      #pragma unroll
      for (int i = 0; i < 3; i++) st[i] = *(const uint4*)(nsrc + (size_t)(tid + 256 * i) * 8);
      if (tid < 128) st[3] = *(const uint4*)(nsrc + (size_t)(tid + 768) * 8);
    }

    float av[4];
    #pragma unroll
    for (int t = 0; t < 4; t++) av[t] = a_s[x][t * 16 + l15];

    #pragma unroll
    for (int h = 0; h < 2; h++) {
      short8 g[4];
      #pragma unroll
      for (int t = 0; t < 4; t++) {
        bf16x8 gv;
        #pragma unroll
        for (int i = 0; i < 8; i++) gv[i] = (__bf16)(av[t] * breg[t][h][i]);
        g[t] = __builtin_bit_cast(short8, gv);
      }
      #pragma unroll
      for (int n = 0; n < 2; n++) {
        int nt = wv * 2 + n;
        if (nt < 7) {
          int r = nt * 16 + l15;
          int phys = (h * 4 + l4) ^ (r & 7);
          short8 wf = __builtin_bit_cast(short8, *(const uint4*)&wbuf[cur][r * 64 + phys * 8]);
          #pragma unroll
          for (int t = 0; t < 4; t++)
            acc[t][n] = __builtin_amdgcn_mfma_f32_16x16x32_bf16(g[t], wf, acc[t][n], 0, 0, 0);
        }
      }
    }

    if (x < 63) {
      #pragma unroll
      for (int i = 0; i < 3; i++) *(uint4*)&wbuf[cur ^ 1][(tid + 256 * i) * 8] = st[i];
      if (tid < 128) *(uint4*)&wbuf[cur ^ 1][(tid + 768) * 8] = st[3];
    }
    __syncthreads();
  }

  #pragma unroll
  for (int n = 0; n < 2; n++) {
    int nt = wv * 2 + n;
    if (nt >= 7) continue;
    int r = nt * 16 + l15;
    if (r >= RRR) continue;
    #pragma unroll
    for (int t = 0; t < 4; t++) {
      int pbase = pt * 64 + t * 16 + l4 * 4;
      #pragma unroll
      for (int q = 0; q < 4; q++) {
        int p = pbase + q;
        if (p < NPAIR) atomicAdd(&out[(size_t)p * RRR + r], acc[t][n][q]);
      }
    }
  }
}

// ---------------------------------------------------------------------------
extern "C" void kernel_launch(void* const* d_in, const int* in_sizes, int n_in,
                              void* d_out, int out_size, void* d_ws, size_t ws_size,
                              hipStream_t stream) {
  const float* context   = (const float*)d_in[0];
  const float* attention = (const float*)d_in[1];
  const float* mmap      = (const float*)d_in[2];
  const float* emap      = (const float*)d_in[3];
  const int*   hts       = (const int*)d_in[4];
  const float* W_h       = (const float*)d_in[5];
  const float* b_h       = (const float*)d_in[6];
  const float* W_t       = (const float*)d_in[7];
  const float* b_t       = (const float*)d_in[8];
  const float* W_node    = (const float*)d_in[9];
  const float* W_ni      = (const float*)d_in[10];
  const float* W_nj      = (const float*)d_in[11];
  const float* W_fij     = (const float*)d_in[12];
  const float* egat_bias = (const float*)d_in[13];
  const float* attn_vec  = (const float*)d_in[14];
  const float* W_rel     = (const float*)d_in[15];
  const float* b_rel     = (const float*)d_in[16];
  float* out = (float*)d_out;

  float* ws = (float*)d_ws;
  size_t o = 0;
  auto alloc = [&](size_t n) { size_t r = o; o += (n + 63) & ~(size_t)63; return r; };
  auto halloc = [&](size_t nshorts) { return alloc((nshorts + 1) / 2); };  // bf16 buffers
  size_t o_mention = alloc((size_t)BB * MMM * DDD);
  size_t o_xb      = halloc((size_t)NNODE * DDD);
  size_t o_em      = alloc((size_t)BB * EEE * LLL);
  size_t o_ea      = alloc((size_t)BB * EEE * HHH * LLL);
  size_t o_cab     = halloc((size_t)NPAIR * LLL);
  size_t o_ctxT    = halloc((size_t)BB * DDD * LLL);
  size_t o_wtni    = halloc((size_t)DDD * DDD);
  size_t o_wtnj    = halloc((size_t)DDD * DDD);
  size_t o_wtnode  = halloc((size_t)DDD * DDD);
  size_t o_wtfij   = halloc((size_t)DDD * DDD);
  size_t o_wth     = halloc((size_t)DDD * 2 * DDD);
  size_t o_wtt     = halloc((size_t)DDD * 2 * DDD);
  size_t o_cinfob  = halloc((size_t)NPAIR * DDD);
  size_t o_fni     = alloc((size_t)NNODE * DDD);
  size_t o_fnj     = alloc((size_t)NNODE * DDD);
  size_t o_fnode   = alloc((size_t)NNODE * DDD);
  size_t o_fout    = alloc((size_t)NEDGE * DDD);
  size_t o_foutb   = halloc((size_t)NEDGE * DDD);
  size_t o_scores  = alloc((size_t)NEDGE * HHH);
  size_t o_nodesb  = halloc((size_t)NNODE * DDD);
  size_t o_newh    = alloc((size_t)NPAIR * DDD);
  size_t o_newt    = alloc((size_t)NPAIR * DDD);
  size_t o_nzl     = alloc((size_t)BB * EEE * LLL);
  size_t o_nzw     = alloc((size_t)BB * EEE * LLL);
  size_t o_nzc     = alloc(128);
  size_t o_tw      = halloc((size_t)768 * 7168);
  (void)ws_size; // ~83 MB used

  float* mention = ws + o_mention;
  unsigned short* xb = (unsigned short*)(ws + o_xb);
  float* em      = ws + o_em;
  float* ea      = ws + o_ea;
  unsigned short* cab    = (unsigned short*)(ws + o_cab);
  unsigned short* ctxT   = (unsigned short*)(ws + o_ctxT);
  unsigned short* wtni   = (unsigned short*)(ws + o_wtni);
  unsigned short* wtnj   = (unsigned short*)(ws + o_wtnj);
  unsigned short* wtnode = (unsigned short*)(ws + o_wtnode);
  unsigned short* wtfij  = (unsigned short*)(ws + o_wtfij);
  unsigned short* wth    = (unsigned short*)(ws + o_wth);
  unsigned short* wtt    = (unsigned short*)(ws + o_wtt);
  unsigned short* cinfob = (unsigned short*)(ws + o_cinfob);
  float* fni     = ws + o_fni;
  float* fnj     = ws + o_fnj;
  float* fnode   = ws + o_fnode;
  float* fout    = ws + o_fout;
  unsigned short* foutb  = (unsigned short*)(ws + o_foutb);
  float* scores  = ws + o_scores;
  unsigned short* nodesb = (unsigned short*)(ws + o_nodesb);
  float* newh    = ws + o_newh;
  float* newt    = ws + o_newt;
  int*   nzl     = (int*)(ws + o_nzl);
  float* nzw     = ws + o_nzw;
  int*   nzc     = (int*)(ws + o_nzc);
  unsigned short* tW = (unsigned short*)(ws + o_tw);

  // ---- one-time weight/context prepasses ----
  k_wprep<<<768, 256, 0, stream>>>(W_rel, tW);
  k_transpose<<<dim3(24, 32, BB), 256, 0, stream>>>(context, ctxT, LLL, DDD);
  k_transpose<<<dim3(24, 24, 1), 256, 0, stream>>>(W_ni, wtni, DDD, DDD);
  k_transpose<<<dim3(24, 24, 1), 256, 0, stream>>>(W_nj, wtnj, DDD, DDD);
  k_transpose<<<dim3(24, 24, 1), 256, 0, stream>>>(W_node, wtnode, DDD, DDD);
  k_transpose<<<dim3(24, 24, 1), 256, 0, stream>>>(W_fij, wtfij, DDD, DDD);
  k_transpose<<<dim3(24, 48, 1), 256, 0, stream>>>(W_h, wth, 2 * DDD, DDD);
  k_transpose<<<dim3(24, 48, 1), 256, 0, stream>>>(W_t, wtt, 2 * DDD, DDD);

  // ---- pooling pipeline ----
  k_mention<<<BB * MMM, 256, 0, stream>>>(context, mmap, mention);
  k_entity<<<BB * EEE, 256, 0, stream>>>(mention, emap, xb);
  k_em<<<BB * EEE, 256, 0, stream>>>(emap, mmap, em);
  k_emnz<<<BB * EEE, 64, 0, stream>>>(em, nzl, nzw, nzc);
  k_ea<<<dim3(EEE, HHH, BB), 256, 0, stream>>>(attention, nzl, nzw, nzc, ea);
  k_ca<<<BB * PPP, 256, 0, stream>>>(ea, hts, cab);

  // ---- MFMA GEMMs ----
  MGArgs gc = {};
  gc.A = cab; gc.BT0 = ctxT; gc.Cb = cinfob; gc.hts = hts; gc.M = PPP; gc.K = LLL;
  k_mgemm<0><<<dim3(7, 6, BB), 256, 0, stream>>>(gc);

  MGArgs gf = {};
  gf.A = xb; gf.BT0 = wtni; gf.BT1 = wtnj; gf.BT2 = wtnode;
  gf.C0 = fni; gf.C1 = fnj; gf.C2 = fnode; gf.M = NNODE; gf.K = DDD;
  k_mgemm<1><<<dim3(1, 6, 3), 256, 0, stream>>>(gf);

  MGArgs gj = {};
  gj.A = cinfob; gj.A2 = xb; gj.BT0 = wtfij; gj.C0 = fout; gj.M = NEDGE; gj.K = DDD;
  k_mgemm<2><<<dim3(29, 6, 1), 256, 0, stream>>>(gj);

  k_scores<<<NEDGE, 256, 0, stream>>>(fout, foutb, fni, fnj, egat_bias, attn_vec, hts, scores);
  k_agg<<<NNODE, 256, 0, stream>>>(scores, fnode, hts, nodesb);

  MGArgs gn = {};
  gn.A2 = foutb; gn.nodes = nodesb; gn.BT0 = wth; gn.BT1 = wtt;
  gn.bias0 = b_h; gn.bias1 = b_t; gn.C0 = newh; gn.C1 = newt;
  gn.hts = hts; gn.M = NPAIR; gn.K = 2 * DDD;
  k_mgemm<3><<<dim3(28, 6, 2), 256, 0, stream>>>(gn);

  // ---- bilinear classifier ----
  k_initout<<<(NPAIR * RRR + 255) / 256, 256, 0, stream>>>(b_rel, out);
  k_bilinear_mfma<<<dim3(55, 12), 256, 0, stream>>>(newh, newt, tW, out);
}

// Round 4
// 507.639 us; speedup vs baseline: 2.6441x; 1.1235x over previous
//
#include <hip/hip_runtime.h>
#include <math.h>

// Problem constants
#define BB 4
#define LLL 1024
#define DDD 768
#define HHH 12
#define EEE 30
#define MMM 60
#define PPP 870
#define RRR 97
#define NNODE 120   // B*E
#define NPAIR 3480  // B*P
#define NEDGE 3600  // NPAIR + NNODE self loops
#define FMIN 1e-10f

typedef __attribute__((ext_vector_type(8))) __bf16 bf16x8;
typedef __attribute__((ext_vector_type(8))) short short8;
typedef __attribute__((ext_vector_type(4))) float f32x4;

static __device__ __forceinline__ unsigned short f2bf(float v) {
  return __builtin_bit_cast(unsigned short, (__bf16)v);
}

// ---------------------------------------------------------------------------
// mention[b,m,d] = exp( sum_l mention_map[b,m,l] * context[b,l,d] )
__global__ __launch_bounds__(256) void k_mention(const float* __restrict__ ctx,
                                                 const float* __restrict__ mmap,
                                                 float* __restrict__ mention) {
  int bm = blockIdx.x;            // b*MMM + m
  int b = bm / MMM;
  const float* mrow = mmap + (size_t)bm * LLL;
  float acc[3] = {0.f, 0.f, 0.f};
  for (int l = 0; l < LLL; l++) {
    float w = mrow[l];
    if (w != 0.f) {
      const float* c = ctx + ((size_t)b * LLL + l) * DDD;
      #pragma unroll
      for (int q = 0; q < 3; q++) acc[q] += w * c[threadIdx.x + 256 * q];
    }
  }
  #pragma unroll
  for (int q = 0; q < 3; q++)
    mention[(size_t)bm * DDD + threadIdx.x + 256 * q] = expf(acc[q]);
}

// x[b,e,d] = log( sum_m entity_map[b,e,m] * mention[b,m,d] )  (0 if empty) -> bf16
__global__ __launch_bounds__(256) void k_entity(const float* __restrict__ mention,
                                                const float* __restrict__ emap,
                                                unsigned short* __restrict__ xb) {
  int be = blockIdx.x;            // b*EEE + e
  int b = be / EEE;
  float acc[3] = {0.f, 0.f, 0.f};
  float cnt = 0.f;
  for (int m = 0; m < MMM; m++) {
    float w = emap[(size_t)be * MMM + m];
    cnt += w;
    if (w != 0.f) {
      const float* mr = mention + ((size_t)b * MMM + m) * DDD;
      #pragma unroll
      for (int q = 0; q < 3; q++) acc[q] += w * mr[threadIdx.x + 256 * q];
    }
  }
  bool empty = (cnt == 0.f);
  #pragma unroll
  for (int q = 0; q < 3; q++)
    xb[(size_t)be * DDD + threadIdx.x + 256 * q] = f2bf(empty ? 0.f : logf(acc[q]));
}

// em[b,e,l] = sum_m entity_map[b,e,m]*mention_map[b,m,l]; normalized over l
__global__ __launch_bounds__(256) void k_em(const float* __restrict__ emap,
                                            const float* __restrict__ mmap,
                                            float* __restrict__ em) {
  int be = blockIdx.x;
  int b = be / EEE;
  int tid = threadIdx.x;
  float acc[4] = {0.f, 0.f, 0.f, 0.f};
  for (int m = 0; m < MMM; m++) {
    float w = emap[(size_t)be * MMM + m];
    if (w != 0.f) {
      const float* mr = mmap + ((size_t)b * MMM + m) * LLL;
      #pragma unroll
      for (int q = 0; q < 4; q++) acc[q] += w * mr[tid + 256 * q];
    }
  }
  __shared__ float red[256];
  red[tid] = acc[0] + acc[1] + acc[2] + acc[3];
  __syncthreads();
  for (int st = 128; st > 0; st >>= 1) {
    if (tid < st) red[tid] += red[tid + st];
    __syncthreads();
  }
  float inv = 1.f / (red[0] + FMIN);
  #pragma unroll
  for (int q = 0; q < 4; q++)
    em[(size_t)be * LLL + tid + 256 * q] = acc[q] * inv;
}

// compact nonzeros of em rows (deterministic order), one wave per row
__global__ __launch_bounds__(64) void k_emnz(const float* __restrict__ em,
                                             int* __restrict__ nzl,
                                             float* __restrict__ nzw,
                                             int* __restrict__ nzc) {
  int be = blockIdx.x;
  int lane = threadIdx.x;
  int base = 0;
  for (int l0 = 0; l0 < LLL; l0 += 64) {
    float w = em[(size_t)be * LLL + l0 + lane];
    unsigned long long mb = __ballot(w != 0.f);
    int pre = __popcll(mb & ((1ull << lane) - 1ull));
    if (w != 0.f) {
      nzl[be * LLL + base + pre] = l0 + lane;
      nzw[be * LLL + base + pre] = w;
    }
    base += __popcll(mb);
  }
  if (lane == 0) nzc[be] = base;
}

// ea[b,e,h,m] = sum_{nz l} w_l * attention[b,h,l,m]
__global__ __launch_bounds__(256) void k_ea(const float* __restrict__ attn,
                                            const int* __restrict__ nzl,
                                            const float* __restrict__ nzw,
                                            const int* __restrict__ nzc,
                                            float* __restrict__ ea) {
  int e = blockIdx.x, h = blockIdx.y, b = blockIdx.z;
  int be = b * EEE + e;
  int cnt = nzc[be];
  float acc[4] = {0.f, 0.f, 0.f, 0.f};
  for (int i = 0; i < cnt; i++) {
    int l = nzl[be * LLL + i];
    float w = nzw[be * LLL + i];
    const float* ar = attn + (((size_t)b * HHH + h) * LLL + l) * LLL;
    #pragma unroll
    for (int q = 0; q < 4; q++) acc[q] += w * ar[threadIdx.x + 256 * q];
  }
  float* er = ea + ((size_t)be * HHH + h) * LLL;
  #pragma unroll
  for (int q = 0; q < 4; q++) er[threadIdx.x + 256 * q] = acc[q];
}

// ca[b,p,l] = sum_h ea[b,hs,h,l]*ea[b,ts,h,l], row-normalized -> bf16
__global__ __launch_bounds__(256) void k_ca(const float* __restrict__ ea,
                                            const int* __restrict__ hts,
                                            unsigned short* __restrict__ cab) {
  int bp = blockIdx.x;            // b*PPP + p
  int b = bp / PPP;
  int hs = hts[bp * 2 + 0], ts = hts[bp * 2 + 1];
  int tid = threadIdx.x;
  const float* eh = ea + ((size_t)(b * EEE + hs) * HHH) * LLL;
  const float* et = ea + ((size_t)(b * EEE + ts) * HHH) * LLL;
  float v[4];
  #pragma unroll
  for (int q = 0; q < 4; q++) {
    int l = tid + 256 * q;
    float s = 0.f;
    #pragma unroll
    for (int h = 0; h < HHH; h++)
      s += eh[(size_t)h * LLL + l] * et[(size_t)h * LLL + l];
    v[q] = s;
  }
  __shared__ float red[256];
  red[tid] = v[0] + v[1] + v[2] + v[3];
  __syncthreads();
  for (int st = 128; st > 0; st >>= 1) {
    if (tid < st) red[tid] += red[tid + st];
    __syncthreads();
  }
  float inv = 1.f / (red[0] + FMIN);
  #pragma unroll
  for (int q = 0; q < 4; q++)
    cab[(size_t)bp * LLL + tid + 256 * q] = f2bf(v[q] * inv);
}

// ---------------------------------------------------------------------------
// transpose + fp32->bf16: src [z][R][C] fp32  ->  dst [z][C][R] bf16
__global__ __launch_bounds__(256) void k_transpose(const float* __restrict__ src,
                                                   unsigned short* __restrict__ dst,
                                                   int R, int C) {
  __shared__ float t_s[32][33];
  int c0 = blockIdx.x * 32, r0 = blockIdx.y * 32;
  const float* s = src + (size_t)blockIdx.z * R * C;
  unsigned short* d = dst + (size_t)blockIdx.z * R * C;
  int tx = threadIdx.x & 31, ty = threadIdx.x >> 5;
  #pragma unroll
  for (int i = 0; i < 4; i++)
    t_s[ty + i * 8][tx] = s[(size_t)(r0 + ty + i * 8) * C + c0 + tx];
  __syncthreads();
  #pragma unroll
  for (int i = 0; i < 4; i++)
    d[(size_t)(c0 + ty + i * 8) * R + r0 + tx] = f2bf(t_s[tx][ty + i * 8]);
}

// ---------------------------------------------------------------------------
// bf16 MFMA GEMM, 128x128 tile, BK=32, 4 waves (2x2), double-buffered LDS.
struct MGArgs {
  const unsigned short *A, *A2, *BT0, *BT1, *BT2, *nodes;
  float *C0, *C1, *C2;
  unsigned short *Cb;
  const float *bias0, *bias1;
  const int *hts;
  int M, K;
};

// MODE 0 CINFO: z=batch. A=cab rows (K=1024), BT=ctxT[z], C=cinfo bf16, ht-mask
// MODE 1 FNX:   z=0/1/2. A=xb (K=768), BT=wt_{ni,nj,node}, C=fni/fnj/fnode fp32
// MODE 2 FFIJ:  A gather row<NPAIR?cinfo:xb, BT=wtfij, C=fout fp32
// MODE 3 NEWHT: z=0/1. A gather k<768?nodesb[hts]:foutb, BT=wt_{h,t}, C=tanh(+bias)
template <int MODE>
__global__ __launch_bounds__(256) void k_mgemm(MGArgs g) {
  __shared__ unsigned short As[2][128 * 32];
  __shared__ unsigned short Bs[2][128 * 32];
  int tid = threadIdx.x;
  int lane = tid & 63;
  int wv = tid >> 6;
  int l15 = lane & 15, l4 = lane >> 4;
  int wr = wv >> 1, wc = wv & 1;
  int row0 = blockIdx.x * 128, col0 = blockIdx.y * 128;
  int bz = blockIdx.z;
  int K = g.K;

  const unsigned short* BTp;
  if (MODE == 0) BTp = g.BT0 + (size_t)bz * DDD * LLL;
  else if (MODE == 1) BTp = bz == 0 ? g.BT0 : (bz == 1 ? g.BT1 : g.BT2);
  else if (MODE == 2) BTp = g.BT0;
  else BTp = bz ? g.BT1 : g.BT0;

  auto aptr = [&](int grow, int k) -> const unsigned short* {
    if (MODE == 0) return g.A + ((size_t)(bz * PPP) + grow) * LLL + k;
    else if (MODE == 1) return g.A + (size_t)grow * DDD + k;
    else if (MODE == 2) return (grow < NPAIR) ? g.A + (size_t)grow * DDD + k
                                              : g.A2 + (size_t)(grow - NPAIR) * DDD + k;
    else {
      if (k < DDD) {
        int b = grow / PPP;
        int node = b * EEE + g.hts[grow * 2 + bz];
        return g.nodes + (size_t)node * DDD + k;
      }
      return g.A2 + (size_t)grow * DDD + (k - DDD);
    }
  };

  uint4 ar[2], br[2];
  auto load_tile = [&](int t) {
    #pragma unroll
    for (int i = 0; i < 2; i++) {
      int idx = i * 256 + tid;
      int row = idx >> 2, gg = idx & 3;
      int grow = row0 + row; if (grow >= g.M) grow = g.M - 1;
      ar[i] = *(const uint4*)aptr(grow, t * 32 + gg * 8);
      br[i] = *(const uint4*)(BTp + (size_t)(col0 + row) * K + t * 32 + gg * 8);
    }
  };
  auto write_tile = [&](int buf) {
    #pragma unroll
    for (int i = 0; i < 2; i++) {
      int idx = i * 256 + tid;
      int row = idx >> 2, gg = idx & 3;
      int phys = gg ^ ((row >> 1) & 3);
      *(uint4*)&As[buf][row * 32 + phys * 8] = ar[i];
      *(uint4*)&Bs[buf][row * 32 + phys * 8] = br[i];
    }
  };

  f32x4 zero = {0.f, 0.f, 0.f, 0.f};
  f32x4 acc[4][4];
  #pragma unroll
  for (int m = 0; m < 4; m++)
    #pragma unroll
    for (int n = 0; n < 4; n++) acc[m][n] = zero;

  int nt = K / 32;
  load_tile(0);
  write_tile(0);
  __syncthreads();
  int cur = 0;
  for (int t = 0; t < nt; t++) {
    if (t + 1 < nt) load_tile(t + 1);
    short8 af[4], bfr[4];
    #pragma unroll
    for (int m = 0; m < 4; m++) {
      int row = wr * 64 + m * 16 + l15;
      int phys = l4 ^ ((row >> 1) & 3);
      af[m] = *(const short8*)&As[cur][row * 32 + phys * 8];
    }
    #pragma unroll
    for (int n = 0; n < 4; n++) {
      int row = wc * 64 + n * 16 + l15;
      int phys = l4 ^ ((row >> 1) & 3);
      bfr[n] = *(const short8*)&Bs[cur][row * 32 + phys * 8];
    }
    #pragma unroll
    for (int m = 0; m < 4; m++)
      #pragma unroll
      for (int n = 0; n < 4; n++)
        acc[m][n] = __builtin_amdgcn_mfma_f32_16x16x32_bf16(af[m], bfr[n], acc[m][n], 0, 0, 0);
    if (t + 1 < nt) {
      write_tile(cur ^ 1);
      __syncthreads();
    }
    cur ^= 1;
  }

  #pragma unroll
  for (int m = 0; m < 4; m++) {
    int rbase = row0 + wr * 64 + m * 16 + l4 * 4;
    #pragma unroll
    for (int n = 0; n < 4; n++) {
      int col = col0 + wc * 64 + n * 16 + l15;
      #pragma unroll
      for (int q = 0; q < 4; q++) {
        int r = rbase + q;
        if (r >= g.M) continue;
        float v = acc[m][n][q];
        if (MODE == 0) {
          size_t grow = (size_t)bz * PPP + r;
          int h0 = g.hts[grow * 2 + 0], h1 = g.hts[grow * 2 + 1];
          float mk = (h0 + h1 != 0) ? 1.f : 0.f;
          g.Cb[grow * DDD + col] = f2bf(v * mk);
        } else if (MODE == 1) {
          float* C = bz == 0 ? g.C0 : (bz == 1 ? g.C1 : g.C2);
          C[(size_t)r * DDD + col] = v;
        } else if (MODE == 2) {
          g.C0[(size_t)r * DDD + col] = v;
        } else {
          float* C = bz ? g.C1 : g.C0;
          const float* bias = bz ? g.bias1 : g.bias0;
          C[(size_t)r * DDD + col] = tanhf(v + bias[col]);
        }
      }
    }
  }
}

// ---------------------------------------------------------------------------
// f_out (in place, fp32) += fni[src]+fnj[dst]+bias ; bf16 copy; per-head scores
__global__ __launch_bounds__(256) void k_scores(float* __restrict__ fout,
                                                unsigned short* __restrict__ foutb,
                                                const float* __restrict__ fni,
                                                const float* __restrict__ fnj,
                                                const float* __restrict__ bias,
                                                const float* __restrict__ avec,
                                                const int* __restrict__ hts,
                                                float* __restrict__ scores) {
  int e = blockIdx.x;
  int srcn, dstn;
  if (e < NPAIR) {
    int b = e / PPP;
    srcn = b * EEE + hts[e * 2 + 0];
    dstn = b * EEE + hts[e * 2 + 1];
  } else {
    srcn = dstn = e - NPAIR;
  }
  int lane = threadIdx.x & 63;
  #pragma unroll
  for (int q = 0; q < 3; q++) {
    int j = threadIdx.x + 256 * q;
    float v = fout[(size_t)e * DDD + j] + fni[(size_t)srcn * DDD + j] +
              fnj[(size_t)dstn * DDD + j] + bias[j];
    fout[(size_t)e * DDD + j] = v;
    foutb[(size_t)e * DDD + j] = f2bf(v);
    float lr = v > 0.f ? v : 0.2f * v;
    float s = lr * avec[j];
    for (int off = 32; off > 0; off >>= 1) s += __shfl_xor(s, off, 64);
    if (lane == 0) scores[e * HHH + (j >> 6)] = s;
  }
}

// per-node edge softmax over in-edges + message aggregation -> nodes bf16
#define ECAP 256
__global__ __launch_bounds__(256) void k_agg(const float* __restrict__ scores,
                                             const float* __restrict__ fnode,
                                             const int* __restrict__ hts,
                                             unsigned short* __restrict__ nodesb) {
  __shared__ int cnt;
  __shared__ int elist[ECAP], slist[ECAP];
  __shared__ float smax[HHH], ssum[HHH];
  __shared__ float alpha[ECAP * HHH];
  int n = blockIdx.x, tid = threadIdx.x;
  if (tid == 0) cnt = 0;
  __syncthreads();
  for (int e = tid; e < NEDGE; e += 256) {
    int srcn, dstn;
    if (e < NPAIR) {
      int b = e / PPP;
      srcn = b * EEE + hts[e * 2 + 0];
      dstn = b * EEE + hts[e * 2 + 1];
    } else {
      srcn = dstn = e - NPAIR;
    }
    if (dstn == n) {
      int i = atomicAdd(&cnt, 1);
      if (i < ECAP) { elist[i] = e; slist[i] = srcn; }
    }
  }
  __syncthreads();
  int c = min(cnt, ECAP);
  if (tid < HHH) {
    float m = -1e30f;
    for (int i = 0; i < c; i++) m = fmaxf(m, scores[elist[i] * HHH + tid]);
    smax[tid] = m;
    float s = 0.f;
    for (int i = 0; i < c; i++) s += expf(scores[elist[i] * HHH + tid] - m);
    ssum[tid] = s;
  }
  __syncthreads();
  for (int t = tid; t < c * HHH; t += 256) {
    int i = t / HHH, h = t - i * HHH;
    alpha[t] = expf(scores[elist[i] * HHH + h] - smax[h]) / ssum[h];
  }
  __syncthreads();
  for (int j = tid; j < DDD; j += 256) {
    int h = j >> 6;
    float acc = 0.f;
    for (int i = 0; i < c; i++)
      acc += alpha[i * HHH + h] * fnode[(size_t)slist[i] * DDD + j];
    nodesb[(size_t)n * DDD + j] = f2bf(acc);
  }
}

// ---------------------------------------------------------------------------
// out[pair,r] = b_rel[r]  (then bilinear atomically accumulates)
__global__ __launch_bounds__(256) void k_initout(const float* __restrict__ brel,
                                                 float* __restrict__ out) {
  int idx = blockIdx.x * 256 + threadIdx.x;
  if (idx < NPAIR * RRR) out[idx] = brel[idx % RRR];
}

// ---------------------------------------------------------------------------
// Prepass: W_rel -> bf16, fragment-major for direct per-wave MFMA B loads.
// Chunk c = k*64+x covers W_rel rows c*64+y (y=0..63). Within a chunk:
// addr = c*8192 + ((nt*2+h)<<9) + lane*8 + i  holds  W[y=32h+8*(lane>>4)+i][r=nt*16+(lane&15)]
// (r in [97,128) zero-padded). One wave MFMA B-fragment = one coalesced 1KB load.
__global__ __launch_bounds__(256) void k_wprep(const float* __restrict__ Wrel,
                                               unsigned short* __restrict__ tW) {
  __shared__ float w_s[64][98];
  int c = blockIdx.x;
  int tid = threadIdx.x;
  for (int idx = tid; idx < 64 * 97; idx += 256) {
    int y = idx / 97, r = idx - y * 97;
    w_s[y][r] = Wrel[(size_t)(c * 64 + y) * RRR + r];
  }
  __syncthreads();
  for (int odx = tid; odx < 8192; odx += 256) {
    int nt = odx >> 10, h = (odx >> 9) & 1, lane = (odx >> 3) & 63, i = odx & 7;
    int y = 32 * h + 8 * (lane >> 4) + i;
    int r = nt * 16 + (lane & 15);
    float v = (r < RRR) ? w_s[y][r] : 0.f;
    tW[(size_t)c * 8192 + odx] = f2bf(v);
  }
}

// ---------------------------------------------------------------------------
// Group-bilinear MFMA GEMM, barrier-free main loop.
// Block = 64 pairs x 1 k-group. Wave w owns n-tiles {w, w+4} (r = nt*16+l15).
// W fragments loaded per-wave directly from fragment-major tW (reg dbuf);
// a staged once in LDS; b hoisted to registers. grid 1D kg-major for L2 reuse.
__global__ __launch_bounds__(256) void k_bilinear_mfma(
    const float* __restrict__ newh, const float* __restrict__ newt,
    const unsigned short* __restrict__ tW, float* __restrict__ out) {
  __shared__ float a_s[64][64];   // [x][p]
  int tid = threadIdx.x;
  int lane = tid & 63;
  int wv = tid >> 6;
  int l15 = lane & 15, l4 = lane >> 4;
  int bid = blockIdx.x;
  int kg = bid / 55, pt = bid - kg * 55;

  // ---- stage a transposed: a_s[x][p] = newh[pt*64+p][kg*64+x] ----
  {
    int pl = tid >> 2, xq = (tid & 3) * 16;
    int prow = pt * 64 + pl; if (prow >= NPAIR) prow = NPAIR - 1;
    const float* src = newh + (size_t)prow * DDD + kg * 64 + xq;
    #pragma unroll
    for (int j4 = 0; j4 < 4; j4++) {
      float4 v = *(const float4*)(src + j4 * 4);
      a_s[xq + j4 * 4 + 0][pl] = v.x;
      a_s[xq + j4 * 4 + 1][pl] = v.y;
      a_s[xq + j4 * 4 + 2][pl] = v.z;
      a_s[xq + j4 * 4 + 3][pl] = v.w;
    }
  }

  // ---- hoist b: breg[t][h][i] = newt[pt*64+t*16+l15][kg*64+32h+8*l4+i] ----
  float breg[4][2][8];
  #pragma unroll
  for (int t = 0; t < 4; t++) {
    int prow = pt * 64 + t * 16 + l15; if (prow >= NPAIR) prow = NPAIR - 1;
    const float* src = newt + (size_t)prow * DDD + kg * 64 + 8 * l4;
    #pragma unroll
    for (int h = 0; h < 2; h++) {
      float4 v0 = *(const float4*)(src + h * 32);
      float4 v1 = *(const float4*)(src + h * 32 + 4);
      breg[t][h][0] = v0.x; breg[t][h][1] = v0.y; breg[t][h][2] = v0.z; breg[t][h][3] = v0.w;
      breg[t][h][4] = v1.x; breg[t][h][5] = v1.y; breg[t][h][6] = v1.z; breg[t][h][7] = v1.w;
    }
  }
  __syncthreads();   // a_s ready; no further barriers

  f32x4 zero = {0.f, 0.f, 0.f, 0.f};
  f32x4 acc[4][2];
  #pragma unroll
  for (int t = 0; t < 4; t++) { acc[t][0] = zero; acc[t][1] = zero; }

  // per-wave W fragment base: lane*8 within each 512-short fragment
  const unsigned short* wp = tW + (size_t)(kg * 64) * 8192 + lane * 8;
  int o00 = (wv * 2 + 0) << 9;          // nt0 = wv,   h=0
  int o01 = (wv * 2 + 1) << 9;          // nt0 = wv,   h=1
  int o10 = ((wv + 4) * 2 + 0) << 9;    // nt1 = wv+4, h=0
  int o11 = ((wv + 4) * 2 + 1) << 9;    // nt1 = wv+4, h=1

  auto loadw = [&](uint4* wf, int x) {
    const unsigned short* p = wp + (size_t)x * 8192;
    wf[0] = *(const uint4*)(p + o00);
    wf[1] = *(const uint4*)(p + o01);
    wf[2] = *(const uint4*)(p + o10);
    wf[3] = *(const uint4*)(p + o11);
  };
  auto step = [&](const uint4* wf, int x) {
    float av[4];
    #pragma unroll
    for (int t = 0; t < 4; t++) av[t] = a_s[x][t * 16 + l15];
    #pragma unroll
    for (int h = 0; h < 2; h++) {
      short8 g[4];
      #pragma unroll
      for (int t = 0; t < 4; t++) {
        bf16x8 gv;
        #pragma unroll
        for (int i = 0; i < 8; i++) gv[i] = (__bf16)(av[t] * breg[t][h][i]);
        g[t] = __builtin_bit_cast(short8, gv);
      }
      short8 w0 = __builtin_bit_cast(short8, wf[h]);
      short8 w1 = __builtin_bit_cast(short8, wf[2 + h]);
      #pragma unroll
      for (int t = 0; t < 4; t++) {
        acc[t][0] = __builtin_amdgcn_mfma_f32_16x16x32_bf16(g[t], w0, acc[t][0], 0, 0, 0);
        acc[t][1] = __builtin_amdgcn_mfma_f32_16x16x32_bf16(g[t], w1, acc[t][1], 0, 0, 0);
      }
    }
  };

  uint4 wa[4], wb[4];
  loadw(wa, 0);
  for (int xx = 0; xx < 64; xx += 2) {
    loadw(wb, xx + 1);
    step(wa, xx);
    if (xx + 2 < 64) loadw(wa, xx + 2);
    step(wb, xx + 1);
  }

  // ---- epilogue: p = pt*64 + t*16 + l4*4 + q ; r = nt*16 + l15 ----
  #pragma unroll
  for (int n = 0; n < 2; n++) {
    int r = (wv + 4 * n) * 16 + l15;
    if (r >= RRR) continue;
    #pragma unroll
    for (int t = 0; t < 4; t++) {
      int pbase = pt * 64 + t * 16 + l4 * 4;
      #pragma unroll
      for (int q = 0; q < 4; q++) {
        int p = pbase + q;
        if (p < NPAIR) atomicAdd(&out[(size_t)p * RRR + r], acc[t][n][q]);
      }
    }
  }
}

// ---------------------------------------------------------------------------
extern "C" void kernel_launch(void* const* d_in, const int* in_sizes, int n_in,
                              void* d_out, int out_size, void* d_ws, size_t ws_size,
                              hipStream_t stream) {
  const float* context   = (const float*)d_in[0];
  const float* attention = (const float*)d_in[1];
  const float* mmap      = (const float*)d_in[2];
  const float* emap      = (const float*)d_in[3];
  const int*   hts       = (const int*)d_in[4];
  const float* W_h       = (const float*)d_in[5];
  const float* b_h       = (const float*)d_in[6];
  const float* W_t       = (const float*)d_in[7];
  const float* b_t       = (const float*)d_in[8];
  const float* W_node    = (const float*)d_in[9];
  const float* W_ni      = (const float*)d_in[10];
  const float* W_nj      = (const float*)d_in[11];
  const float* W_fij     = (const float*)d_in[12];
  const float* egat_bias = (const float*)d_in[13];
  const float* attn_vec  = (const float*)d_in[14];
  const float* W_rel     = (const float*)d_in[15];
  const float* b_rel     = (const float*)d_in[16];
  float* out = (float*)d_out;

  float* ws = (float*)d_ws;
  size_t o = 0;
  auto alloc = [&](size_t n) { size_t r = o; o += (n + 63) & ~(size_t)63; return r; };
  auto halloc = [&](size_t nshorts) { return alloc((nshorts + 1) / 2); };  // bf16 buffers
  size_t o_mention = alloc((size_t)BB * MMM * DDD);
  size_t o_xb      = halloc((size_t)NNODE * DDD);
  size_t o_em      = alloc((size_t)BB * EEE * LLL);
  size_t o_ea      = alloc((size_t)BB * EEE * HHH * LLL);
  size_t o_cab     = halloc((size_t)NPAIR * LLL);
  size_t o_ctxT    = halloc((size_t)BB * DDD * LLL);
  size_t o_wtni    = halloc((size_t)DDD * DDD);
  size_t o_wtnj    = halloc((size_t)DDD * DDD);
  size_t o_wtnode  = halloc((size_t)DDD * DDD);
  size_t o_wtfij   = halloc((size_t)DDD * DDD);
  size_t o_wth     = halloc((size_t)DDD * 2 * DDD);
  size_t o_wtt     = halloc((size_t)DDD * 2 * DDD);
  size_t o_cinfob  = halloc((size_t)NPAIR * DDD);
  size_t o_fni     = alloc((size_t)NNODE * DDD);
  size_t o_fnj     = alloc((size_t)NNODE * DDD);
  size_t o_fnode   = alloc((size_t)NNODE * DDD);
  size_t o_fout    = alloc((size_t)NEDGE * DDD);
  size_t o_foutb   = halloc((size_t)NEDGE * DDD);
  size_t o_scores  = alloc((size_t)NEDGE * HHH);
  size_t o_nodesb  = halloc((size_t)NNODE * DDD);
  size_t o_newh    = alloc((size_t)NPAIR * DDD);
  size_t o_newt    = alloc((size_t)NPAIR * DDD);
  size_t o_nzl     = alloc((size_t)BB * EEE * LLL);
  size_t o_nzw     = alloc((size_t)BB * EEE * LLL);
  size_t o_nzc     = alloc(128);
  size_t o_tw      = halloc((size_t)768 * 8192);   // 12.6 MB fragment-major
  (void)ws_size; // ~84 MB used

  float* mention = ws + o_mention;
  unsigned short* xb = (unsigned short*)(ws + o_xb);
  float* em      = ws + o_em;
  float* ea      = ws + o_ea;
  unsigned short* cab    = (unsigned short*)(ws + o_cab);
  unsigned short* ctxT   = (unsigned short*)(ws + o_ctxT);
  unsigned short* wtni   = (unsigned short*)(ws + o_wtni);
  unsigned short* wtnj   = (unsigned short*)(ws + o_wtnj);
  unsigned short* wtnode = (unsigned short*)(ws + o_wtnode);
  unsigned short* wtfij  = (unsigned short*)(ws + o_wtfij);
  unsigned short* wth    = (unsigned short*)(ws + o_wth);
  unsigned short* wtt    = (unsigned short*)(ws + o_wtt);
  unsigned short* cinfob = (unsigned short*)(ws + o_cinfob);
  float* fni     = ws + o_fni;
  float* fnj     = ws + o_fnj;
  float* fnode   = ws + o_fnode;
  float* fout    = ws + o_fout;
  unsigned short* foutb  = (unsigned short*)(ws + o_foutb);
  float* scores  = ws + o_scores;
  unsigned short* nodesb = (unsigned short*)(ws + o_nodesb);
  float* newh    = ws + o_newh;
  float* newt    = ws + o_newt;
  int*   nzl     = (int*)(ws + o_nzl);
  float* nzw     = ws + o_nzw;
  int*   nzc     = (int*)(ws + o_nzc);
  unsigned short* tW = (unsigned short*)(ws + o_tw);

  // ---- one-time weight/context prepasses ----
  k_wprep<<<768, 256, 0, stream>>>(W_rel, tW);
  k_transpose<<<dim3(24, 32, BB), 256, 0, stream>>>(context, ctxT, LLL, DDD);
  k_transpose<<<dim3(24, 24, 1), 256, 0, stream>>>(W_ni, wtni, DDD, DDD);
  k_transpose<<<dim3(24, 24, 1), 256, 0, stream>>>(W_nj, wtnj, DDD, DDD);
  k_transpose<<<dim3(24, 24, 1), 256, 0, stream>>>(W_node, wtnode, DDD, DDD);
  k_transpose<<<dim3(24, 24, 1), 256, 0, stream>>>(W_fij, wtfij, DDD, DDD);
  k_transpose<<<dim3(24, 48, 1), 256, 0, stream>>>(W_h, wth, 2 * DDD, DDD);
  k_transpose<<<dim3(24, 48, 1), 256, 0, stream>>>(W_t, wtt, 2 * DDD, DDD);

  // ---- pooling pipeline ----
  k_mention<<<BB * MMM, 256, 0, stream>>>(context, mmap, mention);
  k_entity<<<BB * EEE, 256, 0, stream>>>(mention, emap, xb);
  k_em<<<BB * EEE, 256, 0, stream>>>(emap, mmap, em);
  k_emnz<<<BB * EEE, 64, 0, stream>>>(em, nzl, nzw, nzc);
  k_ea<<<dim3(EEE, HHH, BB), 256, 0, stream>>>(attention, nzl, nzw, nzc, ea);
  k_ca<<<BB * PPP, 256, 0, stream>>>(ea, hts, cab);

  // ---- MFMA GEMMs ----
  MGArgs gc = {};
  gc.A = cab; gc.BT0 = ctxT; gc.Cb = cinfob; gc.hts = hts; gc.M = PPP; gc.K = LLL;
  k_mgemm<0><<<dim3(7, 6, BB), 256, 0, stream>>>(gc);

  MGArgs gf = {};
  gf.A = xb; gf.BT0 = wtni; gf.BT1 = wtnj; gf.BT2 = wtnode;
  gf.C0 = fni; gf.C1 = fnj; gf.C2 = fnode; gf.M = NNODE; gf.K = DDD;
  k_mgemm<1><<<dim3(1, 6, 3), 256, 0, stream>>>(gf);

  MGArgs gj = {};
  gj.A = cinfob; gj.A2 = xb; gj.BT0 = wtfij; gj.C0 = fout; gj.M = NEDGE; gj.K = DDD;
  k_mgemm<2><<<dim3(29, 6, 1), 256, 0, stream>>>(gj);

  k_scores<<<NEDGE, 256, 0, stream>>>(fout, foutb, fni, fnj, egat_bias, attn_vec, hts, scores);
  k_agg<<<NNODE, 256, 0, stream>>>(scores, fnode, hts, nodesb);

  MGArgs gn = {};
  gn.A2 = foutb; gn.nodes = nodesb; gn.BT0 = wth; gn.BT1 = wtt;
  gn.bias0 = b_h; gn.bias1 = b_t; gn.C0 = newh; gn.C1 = newt;
  gn.hts = hts; gn.M = NPAIR; gn.K = 2 * DDD;
  k_mgemm<3><<<dim3(28, 6, 2), 256, 0, stream>>>(gn);

  // ---- bilinear classifier ----
  k_initout<<<(NPAIR * RRR + 255) / 256, 256, 0, stream>>>(b_rel, out);
  k_bilinear_mfma<<<55 * 12, 256, 0, stream>>>(newh, newt, tW, out);
}

// Round 5
// 471.624 us; speedup vs baseline: 2.8460x; 1.0764x over previous
//
#include <hip/hip_runtime.h>
#include <math.h>

// Problem constants
#define BB 4
#define LLL 1024
#define DDD 768
#define HHH 12
#define EEE 30
#define MMM 60
#define PPP 870
#define RRR 97
#define NNODE 120   // B*E
#define NPAIR 3480  // B*P
#define NEDGE 3600  // NPAIR + NNODE self loops
#define FMIN 1e-10f

typedef __attribute__((ext_vector_type(8))) __bf16 bf16x8;
typedef __attribute__((ext_vector_type(8))) short short8;
typedef __attribute__((ext_vector_type(4))) float f32x4;

static __device__ __forceinline__ unsigned short f2bf(float v) {
  return __builtin_bit_cast(unsigned short, (__bf16)v);
}

// ---------------------------------------------------------------------------
// mention[b,m,d] = exp( sum_l mention_map[b,m,l] * context[b,l,d] )
// mention_map rows are one-hot: compact nonzeros first (block-parallel),
// then gather — replaces a 1024-iteration serial scan.
__global__ __launch_bounds__(256) void k_mention(const float* __restrict__ ctx,
                                                 const float* __restrict__ mmap,
                                                 float* __restrict__ mention) {
  int bm = blockIdx.x;            // b*MMM + m
  int b = bm / MMM;
  const float* mrow = mmap + (size_t)bm * LLL;
  __shared__ int s_cnt;
  __shared__ int s_l[16];
  __shared__ float s_w[16];
  int tid = threadIdx.x;
  if (tid == 0) s_cnt = 0;
  __syncthreads();
  #pragma unroll
  for (int q = 0; q < 4; q++) {
    int l = tid + 256 * q;
    float w = mrow[l];
    if (w != 0.f) {
      int i = atomicAdd(&s_cnt, 1);
      if (i < 16) { s_l[i] = l; s_w[i] = w; }
    }
  }
  __syncthreads();
  int c = min(s_cnt, 16);
  float acc[3] = {0.f, 0.f, 0.f};
  for (int i = 0; i < c; i++) {
    const float* cr = ctx + ((size_t)b * LLL + s_l[i]) * DDD;
    float w = s_w[i];
    #pragma unroll
    for (int q = 0; q < 3; q++) acc[q] += w * cr[tid + 256 * q];
  }
  #pragma unroll
  for (int q = 0; q < 3; q++)
    mention[(size_t)bm * DDD + tid + 256 * q] = expf(acc[q]);
}

// x[b,e,d] = log( sum_m entity_map[b,e,m] * mention[b,m,d] )  (0 if empty) -> bf16
__global__ __launch_bounds__(256) void k_entity(const float* __restrict__ mention,
                                                const float* __restrict__ emap,
                                                unsigned short* __restrict__ xb) {
  int be = blockIdx.x;            // b*EEE + e
  int b = be / EEE;
  float acc[3] = {0.f, 0.f, 0.f};
  float cnt = 0.f;
  for (int m = 0; m < MMM; m++) {
    float w = emap[(size_t)be * MMM + m];
    cnt += w;
    if (w != 0.f) {
      const float* mr = mention + ((size_t)b * MMM + m) * DDD;
      #pragma unroll
      for (int q = 0; q < 3; q++) acc[q] += w * mr[threadIdx.x + 256 * q];
    }
  }
  bool empty = (cnt == 0.f);
  #pragma unroll
  for (int q = 0; q < 3; q++)
    xb[(size_t)be * DDD + threadIdx.x + 256 * q] = f2bf(empty ? 0.f : logf(acc[q]));
}

// em[b,e,l] = sum_m entity_map[b,e,m]*mention_map[b,m,l]; normalized over l
__global__ __launch_bounds__(256) void k_em(const float* __restrict__ emap,
                                            const float* __restrict__ mmap,
                                            float* __restrict__ em) {
  int be = blockIdx.x;
  int b = be / EEE;
  int tid = threadIdx.x;
  float acc[4] = {0.f, 0.f, 0.f, 0.f};
  for (int m = 0; m < MMM; m++) {
    float w = emap[(size_t)be * MMM + m];
    if (w != 0.f) {
      const float* mr = mmap + ((size_t)b * MMM + m) * LLL;
      #pragma unroll
      for (int q = 0; q < 4; q++) acc[q] += w * mr[tid + 256 * q];
    }
  }
  __shared__ float red[256];
  red[tid] = acc[0] + acc[1] + acc[2] + acc[3];
  __syncthreads();
  for (int st = 128; st > 0; st >>= 1) {
    if (tid < st) red[tid] += red[tid + st];
    __syncthreads();
  }
  float inv = 1.f / (red[0] + FMIN);
  #pragma unroll
  for (int q = 0; q < 4; q++)
    em[(size_t)be * LLL + tid + 256 * q] = acc[q] * inv;
}

// compact nonzeros of em rows (deterministic order), one wave per row
__global__ __launch_bounds__(64) void k_emnz(const float* __restrict__ em,
                                             int* __restrict__ nzl,
                                             float* __restrict__ nzw,
                                             int* __restrict__ nzc) {
  int be = blockIdx.x;
  int lane = threadIdx.x;
  int base = 0;
  for (int l0 = 0; l0 < LLL; l0 += 64) {
    float w = em[(size_t)be * LLL + l0 + lane];
    unsigned long long mb = __ballot(w != 0.f);
    int pre = __popcll(mb & ((1ull << lane) - 1ull));
    if (w != 0.f) {
      nzl[be * LLL + base + pre] = l0 + lane;
      nzw[be * LLL + base + pre] = w;
    }
    base += __popcll(mb);
  }
  if (lane == 0) nzc[be] = base;
}

// ea[b,e,h,m] = sum_{nz l} w_l * attention[b,h,l,m]
__global__ __launch_bounds__(256) void k_ea(const float* __restrict__ attn,
                                            const int* __restrict__ nzl,
                                            const float* __restrict__ nzw,
                                            const int* __restrict__ nzc,
                                            float* __restrict__ ea) {
  int e = blockIdx.x, h = blockIdx.y, b = blockIdx.z;
  int be = b * EEE + e;
  int cnt = nzc[be];
  float acc[4] = {0.f, 0.f, 0.f, 0.f};
  for (int i = 0; i < cnt; i++) {
    int l = nzl[be * LLL + i];
    float w = nzw[be * LLL + i];
    const float* ar = attn + (((size_t)b * HHH + h) * LLL + l) * LLL;
    #pragma unroll
    for (int q = 0; q < 4; q++) acc[q] += w * ar[threadIdx.x + 256 * q];
  }
  float* er = ea + ((size_t)be * HHH + h) * LLL;
  #pragma unroll
  for (int q = 0; q < 4; q++) er[threadIdx.x + 256 * q] = acc[q];
}

// ca[b,p,l] = sum_h ea[b,hs,h,l]*ea[b,ts,h,l], row-normalized -> bf16
__global__ __launch_bounds__(256) void k_ca(const float* __restrict__ ea,
                                            const int* __restrict__ hts,
                                            unsigned short* __restrict__ cab) {
  int bp = blockIdx.x;            // b*PPP + p
  int b = bp / PPP;
  int hs = hts[bp * 2 + 0], ts = hts[bp * 2 + 1];
  int tid = threadIdx.x;
  const float* eh = ea + ((size_t)(b * EEE + hs) * HHH) * LLL;
  const float* et = ea + ((size_t)(b * EEE + ts) * HHH) * LLL;
  float v[4];
  #pragma unroll
  for (int q = 0; q < 4; q++) {
    int l = tid + 256 * q;
    float s = 0.f;
    #pragma unroll
    for (int h = 0; h < HHH; h++)
      s += eh[(size_t)h * LLL + l] * et[(size_t)h * LLL + l];
    v[q] = s;
  }
  __shared__ float red[256];
  red[tid] = v[0] + v[1] + v[2] + v[3];
  __syncthreads();
  for (int st = 128; st > 0; st >>= 1) {
    if (tid < st) red[tid] += red[tid + st];
    __syncthreads();
  }
  float inv = 1.f / (red[0] + FMIN);
  #pragma unroll
  for (int q = 0; q < 4; q++)
    cab[(size_t)bp * LLL + tid + 256 * q] = f2bf(v[q] * inv);
}

// ---------------------------------------------------------------------------
// transpose + fp32->bf16: src [z][R][C] fp32  ->  dst [z][C][R] bf16
__global__ __launch_bounds__(256) void k_transpose(const float* __restrict__ src,
                                                   unsigned short* __restrict__ dst,
                                                   int R, int C) {
  __shared__ float t_s[32][33];
  int c0 = blockIdx.x * 32, r0 = blockIdx.y * 32;
  const float* s = src + (size_t)blockIdx.z * R * C;
  unsigned short* d = dst + (size_t)blockIdx.z * R * C;
  int tx = threadIdx.x & 31, ty = threadIdx.x >> 5;
  #pragma unroll
  for (int i = 0; i < 4; i++)
    t_s[ty + i * 8][tx] = s[(size_t)(r0 + ty + i * 8) * C + c0 + tx];
  __syncthreads();
  #pragma unroll
  for (int i = 0; i < 4; i++)
    d[(size_t)(c0 + ty + i * 8) * R + r0 + tx] = f2bf(t_s[tx][ty + i * 8]);
}

// ---------------------------------------------------------------------------
// bf16 MFMA GEMM, 64x64 tile, BK=64, 4 waves (2x2), double-buffered LDS.
// Small tile => large grid => ~5 blocks/CU so TLP hides the staging latency.
struct MGArgs {
  const unsigned short *A, *A2, *BT0, *BT1, *BT2, *nodes;
  float *C0, *C1, *C2;
  unsigned short *Cb;
  const float *bias0, *bias1;
  const int *hts;
  int M, K;
};

// MODE 0 CINFO: z=batch. A=cab rows (K=1024), BT=ctxT[z], C=cinfo bf16, ht-mask
// MODE 1 FNX:   z=0/1/2. A=xb (K=768), BT=wt_{ni,nj,node}, C=fni/fnj/fnode fp32
// MODE 2 FFIJ:  A gather row<NPAIR?cinfo:xb, BT=wtfij, C=fout fp32
// MODE 3 NEWHT: z=0/1. A gather k<768?nodesb[hts]:foutb, BT=wt_{h,t}, C=tanh(+bias)
template <int MODE>
__global__ __launch_bounds__(256) void k_mgemm(MGArgs g) {
  __shared__ unsigned short As[2][64 * 64];
  __shared__ unsigned short Bs[2][64 * 64];
  int tid = threadIdx.x;
  int lane = tid & 63;
  int wv = tid >> 6;
  int l15 = lane & 15, l4 = lane >> 4;
  int wr = wv >> 1, wc = wv & 1;
  int row0 = blockIdx.x * 64, col0 = blockIdx.y * 64;
  int bz = blockIdx.z;
  int K = g.K;

  const unsigned short* BTp;
  if (MODE == 0) BTp = g.BT0 + (size_t)bz * DDD * LLL;
  else if (MODE == 1) BTp = bz == 0 ? g.BT0 : (bz == 1 ? g.BT1 : g.BT2);
  else if (MODE == 2) BTp = g.BT0;
  else BTp = bz ? g.BT1 : g.BT0;

  auto aptr = [&](int grow, int k) -> const unsigned short* {
    if (MODE == 0) return g.A + ((size_t)(bz * PPP) + grow) * LLL + k;
    else if (MODE == 1) return g.A + (size_t)grow * DDD + k;
    else if (MODE == 2) return (grow < NPAIR) ? g.A + (size_t)grow * DDD + k
                                              : g.A2 + (size_t)(grow - NPAIR) * DDD + k;
    else {
      if (k < DDD) {
        int b = grow / PPP;
        int node = b * EEE + g.hts[grow * 2 + bz];
        return g.nodes + (size_t)node * DDD + k;
      }
      return g.A2 + (size_t)grow * DDD + (k - DDD);
    }
  };

  // 64x64 bf16 tile = 512 granules of 8; 256 threads -> 2 granules each.
  uint4 ar[2], br[2];
  auto load_tile = [&](int t) {
    #pragma unroll
    for (int i = 0; i < 2; i++) {
      int idx = i * 256 + tid;
      int row = idx >> 3, gg = idx & 7;
      int grow = row0 + row; if (grow >= g.M) grow = g.M - 1;
      ar[i] = *(const uint4*)aptr(grow, t * 64 + gg * 8);
      br[i] = *(const uint4*)(BTp + (size_t)(col0 + row) * K + t * 64 + gg * 8);
    }
  };
  auto write_tile = [&](int buf) {
    #pragma unroll
    for (int i = 0; i < 2; i++) {
      int idx = i * 256 + tid;
      int row = idx >> 3, gg = idx & 7;
      int phys = gg ^ (row & 7);
      *(uint4*)&As[buf][row * 64 + phys * 8] = ar[i];
      *(uint4*)&Bs[buf][row * 64 + phys * 8] = br[i];
    }
  };

  f32x4 zero = {0.f, 0.f, 0.f, 0.f};
  f32x4 acc[2][2];
  #pragma unroll
  for (int m = 0; m < 2; m++)
    #pragma unroll
    for (int n = 0; n < 2; n++) acc[m][n] = zero;

  int nt = K / 64;
  load_tile(0);
  write_tile(0);
  __syncthreads();
  int cur = 0;
  for (int t = 0; t < nt; t++) {
    if (t + 1 < nt) load_tile(t + 1);
    short8 af[2][2], bfr[2][2];
    #pragma unroll
    for (int ks = 0; ks < 2; ks++) {
      #pragma unroll
      for (int m = 0; m < 2; m++) {
        int row = wr * 32 + m * 16 + l15;
        int phys = (ks * 4 + l4) ^ (row & 7);
        af[ks][m] = *(const short8*)&As[cur][row * 64 + phys * 8];
      }
      #pragma unroll
      for (int n = 0; n < 2; n++) {
        int row = wc * 32 + n * 16 + l15;
        int phys = (ks * 4 + l4) ^ (row & 7);
        bfr[ks][n] = *(const short8*)&Bs[cur][row * 64 + phys * 8];
      }
    }
    #pragma unroll
    for (int ks = 0; ks < 2; ks++)
      #pragma unroll
      for (int m = 0; m < 2; m++)
        #pragma unroll
        for (int n = 0; n < 2; n++)
          acc[m][n] = __builtin_amdgcn_mfma_f32_16x16x32_bf16(af[ks][m], bfr[ks][n], acc[m][n], 0, 0, 0);
    if (t + 1 < nt) {
      write_tile(cur ^ 1);
      __syncthreads();
    }
    cur ^= 1;
  }

  // epilogue: row = row0 + wr*32 + m*16 + l4*4 + q ; col = col0 + wc*32 + n*16 + l15
  #pragma unroll
  for (int m = 0; m < 2; m++) {
    int rbase = row0 + wr * 32 + m * 16 + l4 * 4;
    #pragma unroll
    for (int n = 0; n < 2; n++) {
      int col = col0 + wc * 32 + n * 16 + l15;
      #pragma unroll
      for (int q = 0; q < 4; q++) {
        int r = rbase + q;
        if (r >= g.M) continue;
        float v = acc[m][n][q];
        if (MODE == 0) {
          size_t grow = (size_t)bz * PPP + r;
          int h0 = g.hts[grow * 2 + 0], h1 = g.hts[grow * 2 + 1];
          float mk = (h0 + h1 != 0) ? 1.f : 0.f;
          g.Cb[grow * DDD + col] = f2bf(v * mk);
        } else if (MODE == 1) {
          float* C = bz == 0 ? g.C0 : (bz == 1 ? g.C1 : g.C2);
          C[(size_t)r * DDD + col] = v;
        } else if (MODE == 2) {
          g.C0[(size_t)r * DDD + col] = v;
        } else {
          float* C = bz ? g.C1 : g.C0;
          const float* bias = bz ? g.bias1 : g.bias0;
          C[(size_t)r * DDD + col] = tanhf(v + bias[col]);
        }
      }
    }
  }
}

// ---------------------------------------------------------------------------
// f_out (in place, fp32) += fni[src]+fnj[dst]+bias ; bf16 copy; per-head scores
__global__ __launch_bounds__(256) void k_scores(float* __restrict__ fout,
                                                unsigned short* __restrict__ foutb,
                                                const float* __restrict__ fni,
                                                const float* __restrict__ fnj,
                                                const float* __restrict__ bias,
                                                const float* __restrict__ avec,
                                                const int* __restrict__ hts,
                                                float* __restrict__ scores) {
  int e = blockIdx.x;
  int srcn, dstn;
  if (e < NPAIR) {
    int b = e / PPP;
    srcn = b * EEE + hts[e * 2 + 0];
    dstn = b * EEE + hts[e * 2 + 1];
  } else {
    srcn = dstn = e - NPAIR;
  }
  int lane = threadIdx.x & 63;
  #pragma unroll
  for (int q = 0; q < 3; q++) {
    int j = threadIdx.x + 256 * q;
    float v = fout[(size_t)e * DDD + j] + fni[(size_t)srcn * DDD + j] +
              fnj[(size_t)dstn * DDD + j] + bias[j];
    fout[(size_t)e * DDD + j] = v;
    foutb[(size_t)e * DDD + j] = f2bf(v);
    float lr = v > 0.f ? v : 0.2f * v;
    float s = lr * avec[j];
    for (int off = 32; off > 0; off >>= 1) s += __shfl_xor(s, off, 64);
    if (lane == 0) scores[e * HHH + (j >> 6)] = s;
  }
}

// per-node edge softmax over in-edges + message aggregation -> nodes bf16
#define ECAP 256
__global__ __launch_bounds__(256) void k_agg(const float* __restrict__ scores,
                                             const float* __restrict__ fnode,
                                             const int* __restrict__ hts,
                                             unsigned short* __restrict__ nodesb) {
  __shared__ int cnt;
  __shared__ int elist[ECAP], slist[ECAP];
  __shared__ float smax[HHH], ssum[HHH];
  __shared__ float alpha[ECAP * HHH];
  int n = blockIdx.x, tid = threadIdx.x;
  if (tid == 0) cnt = 0;
  __syncthreads();
  for (int e = tid; e < NEDGE; e += 256) {
    int srcn, dstn;
    if (e < NPAIR) {
      int b = e / PPP;
      srcn = b * EEE + hts[e * 2 + 0];
      dstn = b * EEE + hts[e * 2 + 1];
    } else {
      srcn = dstn = e - NPAIR;
    }
    if (dstn == n) {
      int i = atomicAdd(&cnt, 1);
      if (i < ECAP) { elist[i] = e; slist[i] = srcn; }
    }
  }
  __syncthreads();
  int c = min(cnt, ECAP);
  if (tid < HHH) {
    float m = -1e30f;
    for (int i = 0; i < c; i++) m = fmaxf(m, scores[elist[i] * HHH + tid]);
    smax[tid] = m;
    float s = 0.f;
    for (int i = 0; i < c; i++) s += expf(scores[elist[i] * HHH + tid] - m);
    ssum[tid] = s;
  }
  __syncthreads();
  for (int t = tid; t < c * HHH; t += 256) {
    int i = t / HHH, h = t - i * HHH;
    alpha[t] = expf(scores[elist[i] * HHH + h] - smax[h]) / ssum[h];
  }
  __syncthreads();
  for (int j = tid; j < DDD; j += 256) {
    int h = j >> 6;
    float acc = 0.f;
    for (int i = 0; i < c; i++)
      acc += alpha[i * HHH + h] * fnode[(size_t)slist[i] * DDD + j];
    nodesb[(size_t)n * DDD + j] = f2bf(acc);
  }
}

// ---------------------------------------------------------------------------
// out[pair,r] = b_rel[r]  (then bilinear atomically accumulates)
__global__ __launch_bounds__(256) void k_initout(const float* __restrict__ brel,
                                                 float* __restrict__ out) {
  int idx = blockIdx.x * 256 + threadIdx.x;
  if (idx < NPAIR * RRR) out[idx] = brel[idx % RRR];
}

// ---------------------------------------------------------------------------
// Prepass: W_rel -> bf16, fragment-major for direct per-wave MFMA B loads.
// addr = c*8192 + ((nt*2+h)<<9) + lane*8 + i holds W[y=32h+8*(lane>>4)+i][r=nt*16+(lane&15)]
__global__ __launch_bounds__(256) void k_wprep(const float* __restrict__ Wrel,
                                               unsigned short* __restrict__ tW) {
  __shared__ float w_s[64][98];
  int c = blockIdx.x;
  int tid = threadIdx.x;
  for (int idx = tid; idx < 64 * 97; idx += 256) {
    int y = idx / 97, r = idx - y * 97;
    w_s[y][r] = Wrel[(size_t)(c * 64 + y) * RRR + r];
  }
  __syncthreads();
  for (int odx = tid; odx < 8192; odx += 256) {
    int nt = odx >> 10, h = (odx >> 9) & 1, lane = (odx >> 3) & 63, i = odx & 7;
    int y = 32 * h + 8 * (lane >> 4) + i;
    int r = nt * 16 + (lane & 15);
    float v = (r < RRR) ? w_s[y][r] : 0.f;
    tW[(size_t)c * 8192 + odx] = f2bf(v);
  }
}

// ---------------------------------------------------------------------------
// Group-bilinear MFMA GEMM, barrier-free main loop.
__global__ __launch_bounds__(256) void k_bilinear_mfma(
    const float* __restrict__ newh, const float* __restrict__ newt,
    const unsigned short* __restrict__ tW, float* __restrict__ out) {
  __shared__ float a_s[64][64];   // [x][p]
  int tid = threadIdx.x;
  int lane = tid & 63;
  int wv = tid >> 6;
  int l15 = lane & 15, l4 = lane >> 4;
  int bid = blockIdx.x;
  int kg = bid / 55, pt = bid - kg * 55;

  {
    int pl = tid >> 2, xq = (tid & 3) * 16;
    int prow = pt * 64 + pl; if (prow >= NPAIR) prow = NPAIR - 1;
    const float* src = newh + (size_t)prow * DDD + kg * 64 + xq;
    #pragma unroll
    for (int j4 = 0; j4 < 4; j4++) {
      float4 v = *(const float4*)(src + j4 * 4);
      a_s[xq + j4 * 4 + 0][pl] = v.x;
      a_s[xq + j4 * 4 + 1][pl] = v.y;
      a_s[xq + j4 * 4 + 2][pl] = v.z;
      a_s[xq + j4 * 4 + 3][pl] = v.w;
    }
  }

  float breg[4][2][8];
  #pragma unroll
  for (int t = 0; t < 4; t++) {
    int prow = pt * 64 + t * 16 + l15; if (prow >= NPAIR) prow = NPAIR - 1;
    const float* src = newt + (size_t)prow * DDD + kg * 64 + 8 * l4;
    #pragma unroll
    for (int h = 0; h < 2; h++) {
      float4 v0 = *(const float4*)(src + h * 32);
      float4 v1 = *(const float4*)(src + h * 32 + 4);
      breg[t][h][0] = v0.x; breg[t][h][1] = v0.y; breg[t][h][2] = v0.z; breg[t][h][3] = v0.w;
      breg[t][h][4] = v1.x; breg[t][h][5] = v1.y; breg[t][h][6] = v1.z; breg[t][h][7] = v1.w;
    }
  }
  __syncthreads();   // a_s ready; no further barriers

  f32x4 zero = {0.f, 0.f, 0.f, 0.f};
  f32x4 acc[4][2];
  #pragma unroll
  for (int t = 0; t < 4; t++) { acc[t][0] = zero; acc[t][1] = zero; }

  const unsigned short* wp = tW + (size_t)(kg * 64) * 8192 + lane * 8;
  int o00 = (wv * 2 + 0) << 9;
  int o01 = (wv * 2 + 1) << 9;
  int o10 = ((wv + 4) * 2 + 0) << 9;
  int o11 = ((wv + 4) * 2 + 1) << 9;

  auto loadw = [&](uint4* wf, int x) {
    const unsigned short* p = wp + (size_t)x * 8192;
    wf[0] = *(const uint4*)(p + o00);
    wf[1] = *(const uint4*)(p + o01);
    wf[2] = *(const uint4*)(p + o10);
    wf[3] = *(const uint4*)(p + o11);
  };
  auto step = [&](const uint4* wf, int x) {
    float av[4];
    #pragma unroll
    for (int t = 0; t < 4; t++) av[t] = a_s[x][t * 16 + l15];
    #pragma unroll
    for (int h = 0; h < 2; h++) {
      short8 g[4];
      #pragma unroll
      for (int t = 0; t < 4; t++) {
        bf16x8 gv;
        #pragma unroll
        for (int i = 0; i < 8; i++) gv[i] = (__bf16)(av[t] * breg[t][h][i]);
        g[t] = __builtin_bit_cast(short8, gv);
      }
      short8 w0 = __builtin_bit_cast(short8, wf[h]);
      short8 w1 = __builtin_bit_cast(short8, wf[2 + h]);
      #pragma unroll
      for (int t = 0; t < 4; t++) {
        acc[t][0] = __builtin_amdgcn_mfma_f32_16x16x32_bf16(g[t], w0, acc[t][0], 0, 0, 0);
        acc[t][1] = __builtin_amdgcn_mfma_f32_16x16x32_bf16(g[t], w1, acc[t][1], 0, 0, 0);
      }
    }
  };

  uint4 wa[4], wb[4];
  loadw(wa, 0);
  for (int xx = 0; xx < 64; xx += 2) {
    loadw(wb, xx + 1);
    step(wa, xx);
    if (xx + 2 < 64) loadw(wa, xx + 2);
    step(wb, xx + 1);
  }

  #pragma unroll
  for (int n = 0; n < 2; n++) {
    int r = (wv + 4 * n) * 16 + l15;
    if (r >= RRR) continue;
    #pragma unroll
    for (int t = 0; t < 4; t++) {
      int pbase = pt * 64 + t * 16 + l4 * 4;
      #pragma unroll
      for (int q = 0; q < 4; q++) {
        int p = pbase + q;
        if (p < NPAIR) atomicAdd(&out[(size_t)p * RRR + r], acc[t][n][q]);
      }
    }
  }
}

// ---------------------------------------------------------------------------
extern "C" void kernel_launch(void* const* d_in, const int* in_sizes, int n_in,
                              void* d_out, int out_size, void* d_ws, size_t ws_size,
                              hipStream_t stream) {
  const float* context   = (const float*)d_in[0];
  const float* attention = (const float*)d_in[1];
  const float* mmap      = (const float*)d_in[2];
  const float* emap      = (const float*)d_in[3];
  const int*   hts       = (const int*)d_in[4];
  const float* W_h       = (const float*)d_in[5];
  const float* b_h       = (const float*)d_in[6];
  const float* W_t       = (const float*)d_in[7];
  const float* b_t       = (const float*)d_in[8];
  const float* W_node    = (const float*)d_in[9];
  const float* W_ni      = (const float*)d_in[10];
  const float* W_nj      = (const float*)d_in[11];
  const float* W_fij     = (const float*)d_in[12];
  const float* egat_bias = (const float*)d_in[13];
  const float* attn_vec  = (const float*)d_in[14];
  const float* W_rel     = (const float*)d_in[15];
  const float* b_rel     = (const float*)d_in[16];
  float* out = (float*)d_out;

  float* ws = (float*)d_ws;
  size_t o = 0;
  auto alloc = [&](size_t n) { size_t r = o; o += (n + 63) & ~(size_t)63; return r; };
  auto halloc = [&](size_t nshorts) { return alloc((nshorts + 1) / 2); };  // bf16 buffers
  size_t o_mention = alloc((size_t)BB * MMM * DDD);
  size_t o_xb      = halloc((size_t)NNODE * DDD);
  size_t o_em      = alloc((size_t)BB * EEE * LLL);
  size_t o_ea      = alloc((size_t)BB * EEE * HHH * LLL);
  size_t o_cab     = halloc((size_t)NPAIR * LLL);
  size_t o_ctxT    = halloc((size_t)BB * DDD * LLL);
  size_t o_wtni    = halloc((size_t)DDD * DDD);
  size_t o_wtnj    = halloc((size_t)DDD * DDD);
  size_t o_wtnode  = halloc((size_t)DDD * DDD);
  size_t o_wtfij   = halloc((size_t)DDD * DDD);
  size_t o_wth     = halloc((size_t)DDD * 2 * DDD);
  size_t o_wtt     = halloc((size_t)DDD * 2 * DDD);
  size_t o_cinfob  = halloc((size_t)NPAIR * DDD);
  size_t o_fni     = alloc((size_t)NNODE * DDD);
  size_t o_fnj     = alloc((size_t)NNODE * DDD);
  size_t o_fnode   = alloc((size_t)NNODE * DDD);
  size_t o_fout    = alloc((size_t)NEDGE * DDD);
  size_t o_foutb   = halloc((size_t)NEDGE * DDD);
  size_t o_scores  = alloc((size_t)NEDGE * HHH);
  size_t o_nodesb  = halloc((size_t)NNODE * DDD);
  size_t o_newh    = alloc((size_t)NPAIR * DDD);
  size_t o_newt    = alloc((size_t)NPAIR * DDD);
  size_t o_nzl     = alloc((size_t)BB * EEE * LLL);
  size_t o_nzw     = alloc((size_t)BB * EEE * LLL);
  size_t o_nzc     = alloc(128);
  size_t o_tw      = halloc((size_t)768 * 8192);   // 12.6 MB fragment-major
  (void)ws_size; // ~84 MB used

  float* mention = ws + o_mention;
  unsigned short* xb = (unsigned short*)(ws + o_xb);
  float* em      = ws + o_em;
  float* ea      = ws + o_ea;
  unsigned short* cab    = (unsigned short*)(ws + o_cab);
  unsigned short* ctxT   = (unsigned short*)(ws + o_ctxT);
  unsigned short* wtni   = (unsigned short*)(ws + o_wtni);
  unsigned short* wtnj   = (unsigned short*)(ws + o_wtnj);
  unsigned short* wtnode = (unsigned short*)(ws + o_wtnode);
  unsigned short* wtfij  = (unsigned short*)(ws + o_wtfij);
  unsigned short* wth    = (unsigned short*)(ws + o_wth);
  unsigned short* wtt    = (unsigned short*)(ws + o_wtt);
  unsigned short* cinfob = (unsigned short*)(ws + o_cinfob);
  float* fni     = ws + o_fni;
  float* fnj     = ws + o_fnj;
  float* fnode   = ws + o_fnode;
  float* fout    = ws + o_fout;
  unsigned short* foutb  = (unsigned short*)(ws + o_foutb);
  float* scores  = ws + o_scores;
  unsigned short* nodesb = (unsigned short*)(ws + o_nodesb);
  float* newh    = ws + o_newh;
  float* newt    = ws + o_newt;
  int*   nzl     = (int*)(ws + o_nzl);
  float* nzw     = ws + o_nzw;
  int*   nzc     = (int*)(ws + o_nzc);
  unsigned short* tW = (unsigned short*)(ws + o_tw);

  // ---- one-time weight/context prepasses ----
  k_wprep<<<768, 256, 0, stream>>>(W_rel, tW);
  k_transpose<<<dim3(24, 32, BB), 256, 0, stream>>>(context, ctxT, LLL, DDD);
  k_transpose<<<dim3(24, 24, 1), 256, 0, stream>>>(W_ni, wtni, DDD, DDD);
  k_transpose<<<dim3(24, 24, 1), 256, 0, stream>>>(W_nj, wtnj, DDD, DDD);
  k_transpose<<<dim3(24, 24, 1), 256, 0, stream>>>(W_node, wtnode, DDD, DDD);
  k_transpose<<<dim3(24, 24, 1), 256, 0, stream>>>(W_fij, wtfij, DDD, DDD);
  k_transpose<<<dim3(24, 48, 1), 256, 0, stream>>>(W_h, wth, 2 * DDD, DDD);
  k_transpose<<<dim3(24, 48, 1), 256, 0, stream>>>(W_t, wtt, 2 * DDD, DDD);

  // ---- pooling pipeline ----
  k_mention<<<BB * MMM, 256, 0, stream>>>(context, mmap, mention);
  k_entity<<<BB * EEE, 256, 0, stream>>>(mention, emap, xb);
  k_em<<<BB * EEE, 256, 0, stream>>>(emap, mmap, em);
  k_emnz<<<BB * EEE, 64, 0, stream>>>(em, nzl, nzw, nzc);
  k_ea<<<dim3(EEE, HHH, BB), 256, 0, stream>>>(attention, nzl, nzw, nzc, ea);
  k_ca<<<BB * PPP, 256, 0, stream>>>(ea, hts, cab);

  // ---- MFMA GEMMs (64x64 tiles) ----
  MGArgs gc = {};
  gc.A = cab; gc.BT0 = ctxT; gc.Cb = cinfob; gc.hts = hts; gc.M = PPP; gc.K = LLL;
  k_mgemm<0><<<dim3(14, 12, BB), 256, 0, stream>>>(gc);

  MGArgs gf = {};
  gf.A = xb; gf.BT0 = wtni; gf.BT1 = wtnj; gf.BT2 = wtnode;
  gf.C0 = fni; gf.C1 = fnj; gf.C2 = fnode; gf.M = NNODE; gf.K = DDD;
  k_mgemm<1><<<dim3(2, 12, 3), 256, 0, stream>>>(gf);

  MGArgs gj = {};
  gj.A = cinfob; gj.A2 = xb; gj.BT0 = wtfij; gj.C0 = fout; gj.M = NEDGE; gj.K = DDD;
  k_mgemm<2><<<dim3(57, 12, 1), 256, 0, stream>>>(gj);

  k_scores<<<NEDGE, 256, 0, stream>>>(fout, foutb, fni, fnj, egat_bias, attn_vec, hts, scores);
  k_agg<<<NNODE, 256, 0, stream>>>(scores, fnode, hts, nodesb);

  MGArgs gn = {};
  gn.A2 = foutb; gn.nodes = nodesb; gn.BT0 = wth; gn.BT1 = wtt;
  gn.bias0 = b_h; gn.bias1 = b_t; gn.C0 = newh; gn.C1 = newt;
  gn.hts = hts; gn.M = NPAIR; gn.K = 2 * DDD;
  k_mgemm<3><<<dim3(55, 12, 2), 256, 0, stream>>>(gn);

  // ---- bilinear classifier ----
  k_initout<<<(NPAIR * RRR + 255) / 256, 256, 0, stream>>>(b_rel, out);
  k_bilinear_mfma<<<55 * 12, 256, 0, stream>>>(newh, newt, tW, out);
}